// Round 11
// baseline (1717.304 us; speedup 1.0000x reference)
//
#include <hip/hip_runtime.h>
#include <hip/hip_bf16.h>

#define DEPTH 6
#define E 1024
#define H 16
#define S 2048
#define V 32000
#define BB 2
#define HD 64
#define NTOK (BB * S)  // 4096

typedef __attribute__((ext_vector_type(8))) short bf16x8;
typedef __attribute__((ext_vector_type(4))) float f32x4;
typedef unsigned short us;

__device__ inline us f2bf(float f) {
    union { float f; unsigned u; } v; v.f = f;
    unsigned r = v.u + 0x7fff + ((v.u >> 16) & 1);
    return (us)(r >> 16);
}
__device__ inline float bf2f(us b) {
    union { unsigned u; float f; } v; v.u = ((unsigned)b) << 16;
    return v.f;
}

__device__ __forceinline__ void gld16(const us* g, us* l) {
    __builtin_amdgcn_global_load_lds(
        (const __attribute__((address_space(1))) unsigned int*)g,
        (__attribute__((address_space(3))) unsigned int*)l, 16, 0, 0);
}

// ---------------------------------------------------------------- f32 -> bf16 cast (nt-loads: weights read once)
__global__ __launch_bounds__(256) void cast_kernel(const float* __restrict__ in,
                                                   us* __restrict__ out, int n8) {
    int i = blockIdx.x * 256 + threadIdx.x;
    if (i >= n8) return;
    f32x4 a = __builtin_nontemporal_load((const f32x4*)in + 2 * (size_t)i);
    f32x4 b = __builtin_nontemporal_load((const f32x4*)in + 2 * (size_t)i + 1);
    uint4 o;
    o.x = f2bf(a[0]) | ((unsigned)f2bf(a[1]) << 16);
    o.y = f2bf(a[2]) | ((unsigned)f2bf(a[3]) << 16);
    o.z = f2bf(b[0]) | ((unsigned)f2bf(b[1]) << 16);
    o.w = f2bf(b[2]) | ((unsigned)f2bf(b[3]) << 16);
    ((uint4*)out)[i] = o;
}

// ---------------------------------------------------------------- fused embedding + first layernorm
__global__ __launch_bounds__(256) void embed_ln(const int* __restrict__ idx,
                                                const float* __restrict__ tok,
                                                const float* __restrict__ pos,
                                                const float* __restrict__ w,
                                                const float* __restrict__ b,
                                                float* __restrict__ x,
                                                us* __restrict__ out) {
    int t = blockIdx.x;
    int s = t & (S - 1);
    int tokid = idx[t];
    int tid = threadIdx.x;
    int c = tid * 4;
    float4 a = *(const float4*)&tok[(size_t)tokid * E + c];
    float4 p = *(const float4*)&pos[(size_t)s * E + c];
    float4 v; v.x = a.x + p.x; v.y = a.y + p.y; v.z = a.z + p.z; v.w = a.w + p.w;
    *(float4*)&x[(size_t)t * E + c] = v;

    float sum = v.x + v.y + v.z + v.w;
    float sq  = v.x * v.x + v.y * v.y + v.z * v.z + v.w * v.w;
    __shared__ float red[8];
    for (int o = 32; o > 0; o >>= 1) { sum += __shfl_xor(sum, o); sq += __shfl_xor(sq, o); }
    int wave = tid >> 6, lane = tid & 63;
    if (lane == 0) { red[wave] = sum; red[4 + wave] = sq; }
    __syncthreads();
    if (tid == 0) {
        red[0] = red[0] + red[1] + red[2] + red[3];
        red[4] = red[4] + red[5] + red[6] + red[7];
    }
    __syncthreads();
    float mean = red[0] * (1.0f / E);
    float var  = red[4] * (1.0f / E) - mean * mean;
    float rstd = rsqrtf(var + 1e-5f);
    float4 wv = *(const float4*)&w[c];
    float4 bv = *(const float4*)&b[c];
    unsigned a0 = f2bf((v.x - mean) * rstd * wv.x + bv.x);
    unsigned a1 = f2bf((v.y - mean) * rstd * wv.y + bv.y);
    unsigned a2 = f2bf((v.z - mean) * rstd * wv.z + bv.z);
    unsigned a3 = f2bf((v.w - mean) * rstd * wv.w + bv.w);
    uint2 o; o.x = a0 | (a1 << 16); o.y = a2 | (a3 << 16);
    *(uint2*)&out[(size_t)t * E + c] = o;
}

// ---------------------------------------------------------------- layernorm
__global__ __launch_bounds__(256) void ln_kernel(const float* __restrict__ x,
                                                 const float* __restrict__ w,
                                                 const float* __restrict__ b,
                                                 us* __restrict__ out) {
    int row = blockIdx.x;
    int tid = threadIdx.x;
    int c = tid * 4;
    float4 v = *(const float4*)&x[(size_t)row * E + c];
    float s  = v.x + v.y + v.z + v.w;
    float sq = v.x * v.x + v.y * v.y + v.z * v.z + v.w * v.w;
    __shared__ float red[8];
    for (int o = 32; o > 0; o >>= 1) { s += __shfl_xor(s, o); sq += __shfl_xor(sq, o); }
    int wave = tid >> 6, lane = tid & 63;
    if (lane == 0) { red[wave] = s; red[4 + wave] = sq; }
    __syncthreads();
    if (tid == 0) {
        red[0] = red[0] + red[1] + red[2] + red[3];
        red[4] = red[4] + red[5] + red[6] + red[7];
    }
    __syncthreads();
    float mean = red[0] * (1.0f / E);
    float var  = red[4] * (1.0f / E) - mean * mean;
    float rstd = rsqrtf(var + 1e-5f);
    float4 wv = *(const float4*)&w[c];
    float4 bv = *(const float4*)&b[c];
    unsigned a0 = f2bf((v.x - mean) * rstd * wv.x + bv.x);
    unsigned a1 = f2bf((v.y - mean) * rstd * wv.y + bv.y);
    unsigned a2 = f2bf((v.z - mean) * rstd * wv.z + bv.z);
    unsigned a3 = f2bf((v.w - mean) * rstd * wv.w + bv.w);
    uint2 o; o.x = a0 | (a1 << 16); o.y = a2 | (a3 << 16);
    *(uint2*)&out[(size_t)row * E + c] = o;
}

// ---------------------------------------------------------------- fused ff2-combine (4 partials) + layernorm
__global__ __launch_bounds__(256) void combine_ln(const us* __restrict__ p012,
                                                  const us* __restrict__ p3,
                                                  const float* __restrict__ bias,
                                                  float* __restrict__ x,
                                                  const float* __restrict__ w,
                                                  const float* __restrict__ b,
                                                  us* __restrict__ out) {
    int row = blockIdx.x;
    int tid = threadIdx.x;
    int c = tid * 4;
    size_t base = (size_t)row * E + c;
    const size_t stride = (size_t)NTOK * E;
    float4 v = *(const float4*)&x[base];
    uint2 a0 = *(const uint2*)&p012[base];
    uint2 a1 = *(const uint2*)&p012[base + stride];
    uint2 a2 = *(const uint2*)&p012[base + 2 * stride];
    uint2 a3 = *(const uint2*)&p3[base];
    float4 bi = *(const float4*)&bias[c];
    v.x += bf2f((us)(a0.x & 0xffff)) + bf2f((us)(a1.x & 0xffff)) + bf2f((us)(a2.x & 0xffff)) + bf2f((us)(a3.x & 0xffff)) + bi.x;
    v.y += bf2f((us)(a0.x >> 16))    + bf2f((us)(a1.x >> 16))    + bf2f((us)(a2.x >> 16))    + bf2f((us)(a3.x >> 16))    + bi.y;
    v.z += bf2f((us)(a0.y & 0xffff)) + bf2f((us)(a1.y & 0xffff)) + bf2f((us)(a2.y & 0xffff)) + bf2f((us)(a3.y & 0xffff)) + bi.z;
    v.w += bf2f((us)(a0.y >> 16))    + bf2f((us)(a1.y >> 16))    + bf2f((us)(a2.y >> 16))    + bf2f((us)(a3.y >> 16))    + bi.w;
    *(float4*)&x[base] = v;

    float s  = v.x + v.y + v.z + v.w;
    float sq = v.x * v.x + v.y * v.y + v.z * v.z + v.w * v.w;
    __shared__ float red[8];
    for (int o = 32; o > 0; o >>= 1) { s += __shfl_xor(s, o); sq += __shfl_xor(sq, o); }
    int wave = tid >> 6, lane = tid & 63;
    if (lane == 0) { red[wave] = s; red[4 + wave] = sq; }
    __syncthreads();
    if (tid == 0) {
        red[0] = red[0] + red[1] + red[2] + red[3];
        red[4] = red[4] + red[5] + red[6] + red[7];
    }
    __syncthreads();
    float mean = red[0] * (1.0f / E);
    float var  = red[4] * (1.0f / E) - mean * mean;
    float rstd = rsqrtf(var + 1e-5f);
    float4 wv = *(const float4*)&w[c];
    float4 bv = *(const float4*)&b[c];
    unsigned b0 = f2bf((v.x - mean) * rstd * wv.x + bv.x);
    unsigned b1 = f2bf((v.y - mean) * rstd * wv.y + bv.y);
    unsigned b2 = f2bf((v.z - mean) * rstd * wv.z + bv.z);
    unsigned b3 = f2bf((v.w - mean) * rstd * wv.w + bv.w);
    uint2 o; o.x = b0 | (b1 << 16); o.y = b2 | (b3 << 16);
    *(uint2*)&out[base] = o;
}

// ================================================================ 256x256 8-phase GEMM (T2+T3+T4+T5)
// ISVM: 0 = none, 1 = vmcnt(6), 2 = vmcnt(0) (peeled-tail drain)
#define GPH(dd, fb, STAGE, ISVM, IS12)                                              \
  {                                                                                 \
    bf16x8 afr0[2], afr1[2];                                                        \
    if ((fb) == 0) {                                                                \
      _Pragma("unroll")                                                             \
      for (int n = 0; n < 4; n++)                                                   \
        _Pragma("unroll")                                                           \
        for (int ks = 0; ks < 2; ks++)                                              \
          bfr[n][ks] = *(const bf16x8*)&lds[32768 + (dd) * 16384 +                  \
              (brow + n * 16) * 64 + ((ks * 4 + g4) ^ xg) * 8];                     \
    }                                                                               \
    _Pragma("unroll")                                                               \
    for (int ks = 0; ks < 2; ks++) {                                                \
      afr0[ks] = *(const bf16x8*)&lds[(dd) * 16384 + ((fb) >> 1) * 4096 +           \
          arow0 * 64 + ((ks * 4 + g4) ^ xg) * 8];                                   \
      afr1[ks] = *(const bf16x8*)&lds[(dd) * 16384 + ((fb) >> 1) * 4096 +           \
          arow1 * 64 + ((ks * 4 + g4) ^ xg) * 8];                                   \
    }                                                                               \
    STAGE;                                                                          \
    __builtin_amdgcn_sched_barrier(0);                                              \
    if (IS12) asm volatile("s_waitcnt lgkmcnt(8)" ::: "memory");                    \
    __builtin_amdgcn_s_barrier();                                                   \
    asm volatile("s_waitcnt lgkmcnt(0)" ::: "memory");                              \
    __builtin_amdgcn_sched_barrier(0);                                              \
    __builtin_amdgcn_s_setprio(1);                                                  \
    _Pragma("unroll")                                                               \
    for (int n = 0; n < 4; n++)                                                     \
      _Pragma("unroll")                                                             \
      for (int ks = 0; ks < 2; ks++) {                                              \
        acc[(fb)][n]     = __builtin_amdgcn_mfma_f32_16x16x32_bf16(afr0[ks], bfr[n][ks], acc[(fb)][n], 0, 0, 0);     \
        acc[(fb) + 1][n] = __builtin_amdgcn_mfma_f32_16x16x32_bf16(afr1[ks], bfr[n][ks], acc[(fb) + 1][n], 0, 0, 0); \
      }                                                                             \
    __builtin_amdgcn_s_setprio(0);                                                  \
    __builtin_amdgcn_sched_barrier(0);                                              \
    if ((ISVM) == 1) asm volatile("s_waitcnt vmcnt(6)" ::: "memory");               \
    if ((ISVM) == 2) asm volatile("s_waitcnt vmcnt(0)" ::: "memory");               \
    __builtin_amdgcn_s_barrier();                                                   \
  }

// SPLITK=0: sw -> (bm,bn) M-fastest. SPLITK=1: grid = ntile*4, kz chunks of K;
// partial kz<3 -> outp + kz*M*ldo (bf16), kz==3 -> outp3.
template <int OUT_BF16, int ACT_GELU, int HAS_BIAS, int SPLITK>
__global__ __launch_bounds__(512, 2) void gemm256(const us* __restrict__ A, int lda,
                                                  const us* __restrict__ Bw, int ldb,
                                                  const float* __restrict__ bias,
                                                  void* __restrict__ outp,
                                                  void* __restrict__ outp3,
                                                  int M, int N, int K, int ldo) {
    __shared__ us lds[65536];
    int tid = threadIdx.x;
    int nwg = gridDim.x;
    int wgid = blockIdx.x;
    int chunk = nwg >> 3;
    int sw = (wgid & 7) * chunk + (wgid >> 3);
    int MB = M >> 8;
    int bm, bn;
    us* outb;
    float* outf = (float*)outp;
    if (SPLITK) {
        int ntile = MB * (N >> 8);
        int kz = sw / ntile;
        int rem = sw % ntile;
        bm = (rem % MB) * 256;
        bn = (rem / MB) * 256;
        A  += (size_t)kz * K;
        Bw += (size_t)kz * K;
        outb = (kz < 3) ? (us*)outp + (size_t)kz * M * ldo : (us*)outp3;
    } else {
        bm = (sw % MB) * 256;
        bn = (sw / MB) * 256;
        outb = (us*)outp;
    }
    int w = tid >> 6, lane = tid & 63;
    int wr = w >> 2, wc = w & 3;
    int l15 = lane & 15, g4 = lane >> 4;
    int xg = l15 & 7;
    int arow0 = (wr ? 32 : 0) + l15;
    int arow1 = arow0 + 16;
    int brow = wc * 64 + l15;
    int NT = K >> 6;

    f32x4 acc[8][4] = {};
    bf16x8 bfr[4][2];

    auto stA = [&](int u, int dd, int h) {
        #pragma unroll
        for (int i = 0; i < 2; i++) {
            int k = tid + i * 512;
            int q = 2 * h + (k >> 9);
            int r = (k >> 3) & 63;
            int tr = q * 32 + (r & 31) + ((r >> 5) << 7);
            int gp = (k & 7) ^ (r & 7);
            gld16(A + (size_t)(bm + tr) * lda + u * 64 + gp * 8,
                  &lds[dd * 16384 + h * 8192 + k * 8]);
        }
    };
    auto stB = [&](int u, int dd, int h) {
        #pragma unroll
        for (int i = 0; i < 2; i++) {
            int k = tid + i * 512;
            int row = h * 128 + (k >> 3);
            int gp = (k & 7) ^ ((k >> 3) & 7);
            gld16(Bw + (size_t)(bn + row) * ldb + u * 64 + gp * 8,
                  &lds[32768 + dd * 16384 + h * 8192 + k * 8]);
        }
    };

    stB(0, 0, 0); stB(0, 0, 1); stA(0, 0, 0); stA(0, 0, 1);
    stB(1, 1, 0); stB(1, 1, 1); stA(1, 1, 0);
    __builtin_amdgcn_sched_barrier(0);
    asm volatile("s_waitcnt vmcnt(6)" ::: "memory");
    __builtin_amdgcn_s_barrier();

    #pragma unroll 1
    for (int t = 0; t < NT - 2; t += 2) {
        GPH(0, 0, stA(t + 1, 1, 1), 0, 1)
        GPH(0, 2, stB(t + 2, 0, 0), 0, 0)
        GPH(0, 4, stB(t + 2, 0, 1), 0, 0)
        GPH(0, 6, stA(t + 2, 0, 0), 1, 0)
        GPH(1, 0, stA(t + 2, 0, 1), 0, 1)
        GPH(1, 2, stB(t + 3, 1, 0), 0, 0)
        GPH(1, 4, stB(t + 3, 1, 1), 0, 0)
        GPH(1, 6, stA(t + 3, 1, 0), 1, 0)
    }
    // peeled final iteration (tiles NT-2, NT-1): no beyond-range prefetch.
    // P1 stages the one remaining real half-tile; P4 drains all (8 in flight).
    GPH(0, 0, stA(NT - 1, 1, 1), 0, 1)
    GPH(0, 2, , 0, 0)
    GPH(0, 4, , 0, 0)
    GPH(0, 6, , 2, 0)
    GPH(1, 0, , 0, 1)
    GPH(1, 2, , 0, 0)
    GPH(1, 4, , 0, 0)
    GPH(1, 6, , 0, 0)

    #pragma unroll
    for (int mf = 0; mf < 8; mf++)
        #pragma unroll
        for (int n = 0; n < 4; n++)
            #pragma unroll
            for (int j = 0; j < 4; j++) {
                int r = bm + wr * 128 + mf * 16 + g4 * 4 + j;
                int c = bn + wc * 64 + n * 16 + l15;
                float v = acc[mf][n][j];
                if (HAS_BIAS) v += bias[c];
                if (ACT_GELU) v = 0.5f * v * (1.0f + erff(v * 0.70710678118f));
                if (OUT_BF16) outb[(size_t)r * ldo + c] = f2bf(v);
                else __builtin_nontemporal_store(v, &outf[(size_t)r * ldo + c]);
            }
}

// ---------------------------------------------------------------- V transpose
__global__ __launch_bounds__(256) void transpose_v(const us* __restrict__ qkv,
                                                   us* __restrict__ vT) {
    int kt = blockIdx.x, h = blockIdx.y, b = blockIdx.z;
    int tid = threadIdx.x;
    __shared__ us T[64][72];
    const size_t base = (size_t)b * S * 3072 + 2048 + h * 64;
    int k0 = kt * 64;
    #pragma unroll
    for (int it = 0; it < 2; it++) {
        int p = tid + it * 256;
        int key = p & 63, c8 = (p >> 6) * 8;
        uint4 v = *(const uint4*)&qkv[base + (size_t)(k0 + key) * 3072 + c8];
        us* pv = (us*)&v;
        #pragma unroll
        for (int e = 0; e < 8; e++) T[c8 + e][key] = pv[e];
    }
    __syncthreads();
    const size_t obase = ((size_t)(b * H + h) * 64) * S + k0;
    #pragma unroll
    for (int it = 0; it < 2; it++) {
        int o = tid + it * 256;
        int d = o >> 3, cc = (o & 7) * 8;
        uint4 v = *(const uint4*)&T[d][cc];
        *(uint4*)&vT[obase + (size_t)d * S + cc] = v;
    }
}

// ---------------------------------------------------------------- flash attention: 8 waves, QBLK=128, KVB=64
// causal load-balance: b==1 blocks take reversed qt so each CU pairs heavy+light
__global__ __launch_bounds__(512, 4) void attn_kernel(const us* __restrict__ qkv,
                                                      const us* __restrict__ vT,
                                                      float* __restrict__ x) {
    int qt = blockIdx.x, h = blockIdx.y, b = blockIdx.z;
    if (b == 1) qt = (S / 128 - 1) - qt;   // heavy+light pairing per CU
    int tid = threadIdx.x;
    int w = tid >> 6, lane = tid & 63;
    int l15 = lane & 15, g4 = lane >> 4;
    int s0 = qt * 128;
    int qrow_base = s0 + w * 16;
    const size_t qbase = (size_t)b * S * 3072;
    const size_t vtbase = ((size_t)(b * H + h) * 64) * S;

    __shared__ us K_lds[2][64 * 64];
    __shared__ us VT_lds[2][64 * 64];
    __shared__ us P_lds[8][16 * 72];

    bf16x8 q[2];
    #pragma unroll
    for (int dc = 0; dc < 2; dc++) {
        q[dc] = *(const bf16x8*)&qkv[qbase + (size_t)(qrow_base + l15) * 3072 + h * 64 + dc * 32 + 8 * g4];
        us* qq = (us*)&q[dc];
        #pragma unroll
        for (int e = 0; e < 8; e++) qq[e] = f2bf(bf2f(qq[e]) * 0.125f);  // fold 1/sqrt(d)
    }

    f32x4 O[4] = {};
    float m_run[4], l_part[4];
    #pragma unroll
    for (int j = 0; j < 4; j++) { m_run[j] = -INFINITY; l_part[j] = 0.0f; }

    int lastt = 2 * qt + 1;
    {
        int p = tid, row = p >> 3, cc = p & 7;
        int scc = cc ^ (row & 7);
        gld16(&qkv[qbase + (size_t)(0 + row) * 3072 + 1024 + h * 64 + scc * 8], &K_lds[0][p * 8]);
        gld16(&vT[vtbase + (size_t)row * S + 0 + scc * 8], &VT_lds[0][p * 8]);
    }
    __syncthreads();

    for (int t = 0; t <= lastt; t++) {
        int bb = t & 1;
        if (t < lastt) {
            int p = tid, row = p >> 3, cc = p & 7;
            int scc = cc ^ (row & 7);
            gld16(&qkv[qbase + (size_t)((t + 1) * 64 + row) * 3072 + 1024 + h * 64 + scc * 8], &K_lds[bb ^ 1][p * 8]);
            gld16(&vT[vtbase + (size_t)row * S + (t + 1) * 64 + scc * 8], &VT_lds[bb ^ 1][p * 8]);
        }
        int k0 = t * 64;
        if (k0 <= qrow_base + 15) {
            f32x4 sf[4];
            __builtin_amdgcn_s_setprio(1);
            #pragma unroll
            for (int c = 0; c < 4; c++) {
                f32x4 z = {};
                int row = c * 16 + l15;
                #pragma unroll
                for (int dc = 0; dc < 2; dc++) {
                    int ch = (dc * 4 + g4) ^ (row & 7);
                    bf16x8 kb = *(const bf16x8*)&K_lds[bb][row * 64 + ch * 8];
                    z = __builtin_amdgcn_mfma_f32_16x16x32_bf16(q[dc], kb, z, 0, 0, 0);
                }
                sf[c] = z;
            }
            __builtin_amdgcn_s_setprio(0);
            bool needmask = (k0 + 63 > qrow_base);
            float vv[4][4], tmr[4];
            #pragma unroll
            for (int j = 0; j < 4; j++) {
                int qrow = qrow_base + g4 * 4 + j;
                float v0 = sf[0][j], v1 = sf[1][j];
                float v2 = sf[2][j], v3 = sf[3][j];
                if (needmask) {
                    if (k0 +      l15 > qrow) v0 = -INFINITY;
                    if (k0 + 16 + l15 > qrow) v1 = -INFINITY;
                    if (k0 + 32 + l15 > qrow) v2 = -INFINITY;
                    if (k0 + 48 + l15 > qrow) v3 = -INFINITY;
                }
                float tm = fmaxf(fmaxf(v0, v1), fmaxf(v2, v3));
                tm = fmaxf(tm, __shfl_xor(tm, 1, 16));
                tm = fmaxf(tm, __shfl_xor(tm, 2, 16));
                tm = fmaxf(tm, __shfl_xor(tm, 4, 16));
                tm = fmaxf(tm, __shfl_xor(tm, 8, 16));
                tmr[j] = tm;
                vv[0][j] = v0; vv[1][j] = v1; vv[2][j] = v2; vv[3][j] = v3;
            }
            bool grow = (tmr[0] > m_run[0] + 8.0f) || (tmr[1] > m_run[1] + 8.0f) ||
                        (tmr[2] > m_run[2] + 8.0f) || (tmr[3] > m_run[3] + 8.0f);
            bool skip = !__any(grow);
            float pr[4][4], alpha[4];
            #pragma unroll
            for (int j = 0; j < 4; j++) {
                float mnew = skip ? m_run[j] : fmaxf(m_run[j], tmr[j]);
                float p0 = __expf(vv[0][j] - mnew), p1 = __expf(vv[1][j] - mnew);
                float p2 = __expf(vv[2][j] - mnew), p3 = __expf(vv[3][j] - mnew);
                float sum4 = (p0 + p1) + (p2 + p3);
                if (skip) {
                    l_part[j] += sum4;
                } else {
                    alpha[j] = __expf(m_run[j] - mnew);
                    l_part[j] = l_part[j] * alpha[j] + sum4;
                    m_run[j] = mnew;
                }
                pr[0][j] = p0; pr[1][j] = p1; pr[2][j] = p2; pr[3][j] = p3;
            }
            if (!skip) {
                #pragma unroll
                for (int f = 0; f < 4; f++)
                    #pragma unroll
                    for (int j = 0; j < 4; j++) O[f][j] *= alpha[j];
            }
            us* Pw = &P_lds[w][0];
            #pragma unroll
            for (int c = 0; c < 4; c++)
                #pragma unroll
                for (int j = 0; j < 4; j++)
                    Pw[(g4 * 4 + j) * 72 + c * 16 + l15] = f2bf(pr[c][j]);
            __builtin_amdgcn_s_setprio(1);
            #pragma unroll
            for (int kc = 0; kc < 2; kc++) {
                bf16x8 pa = *(const bf16x8*)&Pw[l15 * 72 + kc * 32 + g4 * 8];
                #pragma unroll
                for (int dt = 0; dt < 4; dt++) {
                    int row = dt * 16 + l15;
                    int ch = (kc * 4 + g4) ^ (row & 7);
                    bf16x8 vb = *(const bf16x8*)&VT_lds[bb][row * 64 + ch * 8];
                    O[dt] = __builtin_amdgcn_mfma_f32_16x16x32_bf16(pa, vb, O[dt], 0, 0, 0);
                }
            }
            __builtin_amdgcn_s_setprio(0);
        }
        __syncthreads();
    }
    float l_run[4];
    #pragma unroll
    for (int j = 0; j < 4; j++) {
        float l = l_part[j];
        l += __shfl_xor(l, 1, 16);
        l += __shfl_xor(l, 2, 16);
        l += __shfl_xor(l, 4, 16);
        l += __shfl_xor(l, 8, 16);
        l_run[j] = l;
    }
    #pragma unroll
    for (int dt = 0; dt < 4; dt++)
        #pragma unroll
        for (int j = 0; j < 4; j++) {
            size_t o = ((size_t)b * S + qrow_base + g4 * 4 + j) * E + h * 64 + dt * 16 + l15;
            x[o] += O[dt][j] / l_run[j];
        }
}

// ---------------------------------------------------------------- launch
extern "C" void kernel_launch(void* const* d_in, const int* in_sizes, int n_in,
                              void* d_out, int out_size, void* d_ws, size_t ws_size,
                              hipStream_t stream) {
    const int*   idx    = (const int*)d_in[0];
    const float* tok    = (const float*)d_in[1];
    const float* pos    = (const float*)d_in[2];
    const float* qkv_w  = (const float*)d_in[3];
    const float* qkv_b  = (const float*)d_in[4];
    const float* ln1_w  = (const float*)d_in[5];
    const float* ln1_b  = (const float*)d_in[6];
    const float* ln2_w  = (const float*)d_in[7];
    const float* ln2_b  = (const float*)d_in[8];
    const float* ff1_w  = (const float*)d_in[9];
    const float* ff1_b  = (const float*)d_in[10];
    const float* ff2_w  = (const float*)d_in[11];
    const float* ff2_b  = (const float*)d_in[12];
    const float* fin_w  = (const float*)d_in[13];
    const float* fin_b  = (const float*)d_in[14];
    const float* proj_w = (const float*)d_in[15];

    char* ws = (char*)d_ws;
    float* x    = (float*)ws;                          // 16.78 MB f32 residual
    us*    xn   = (us*)(ws + 16777216);                // 8.39 MB bf16 LN out
    us*    qkvb = (us*)(ws + 25165824);                // 25.17 MB bf16 qkv / ff2 partials 0-2
    us*    hbuf = (us*)(ws + 50331648);                // 33.55 MB bf16 ff hidden
    us*    wbuf = (us*)(ws + 83886080);                // 8.39 MB bf16 per-layer weights
    us*    vTb  = (us*)(ws + 92274688);                // 8.39 MB bf16 V^T / ff2 partial 3
    us*    pbuf = qkvb;                                // 65.5 MB proj weights (qkvb..wbuf span, free then)

    embed_ln<<<NTOK, 256, 0, stream>>>(idx, tok, pos, ln1_w, ln1_b, x, xn);
    for (int l = 0; l < DEPTH; l++) {
        cast_kernel<<<1536, 256, 0, stream>>>(qkv_w + (size_t)l * 3 * E * E, wbuf, 3 * E * E / 8);
        gemm256<1, 0, 1, 0><<<192, 512, 0, stream>>>(
            xn, E, wbuf, E, qkv_b + l * 3 * E, qkvb, nullptr, NTOK, 3 * E, E, 3 * E);
        transpose_v<<<dim3(S / 64, H, BB), 256, 0, stream>>>(qkvb, vTb);
        attn_kernel<<<dim3(S / 128, H, BB), 512, 0, stream>>>(qkvb, vTb, x);
        ln_kernel<<<NTOK, 256, 0, stream>>>(x, ln2_w + l * E, ln2_b + l * E, xn);
        cast_kernel<<<2048, 256, 0, stream>>>(ff1_w + (size_t)l * 4 * E * E, wbuf, 4 * E * E / 8);
        gemm256<1, 1, 1, 0><<<256, 512, 0, stream>>>(
            xn, E, wbuf, E, ff1_b + l * 4 * E, hbuf, nullptr, NTOK, 4 * E, E, 4 * E);
        cast_kernel<<<2048, 256, 0, stream>>>(ff2_w + (size_t)l * E * 4 * E, wbuf, 4 * E * E / 8);
        // ff2: 256^2 8-phase split-K x4 (grid 256 = 1 block/CU), bf16 partials
        gemm256<1, 0, 0, 1><<<256, 512, 0, stream>>>(
            hbuf, 4 * E, wbuf, 4 * E, nullptr, qkvb, vTb, NTOK, E, E, E);
        const float* nw = (l < DEPTH - 1) ? (ln1_w + (l + 1) * E) : fin_w;
        const float* nb = (l < DEPTH - 1) ? (ln1_b + (l + 1) * E) : fin_b;
        combine_ln<<<NTOK, 256, 0, stream>>>(qkvb, vTb, ff2_b + l * E, x, nw, nb, xn);
    }
    cast_kernel<<<16000, 256, 0, stream>>>(proj_w, pbuf, V * E / 8);
    gemm256<0, 0, 0, 0><<<1024, 512, 0, stream>>>(
        xn, E, pbuf, E, nullptr, d_out, nullptr, NTOK, 16384, E, V);
    gemm256<0, 0, 0, 0><<<976, 512, 0, stream>>>(
        xn, E, pbuf + (size_t)16384 * E, E, nullptr, (float*)d_out + 16384, nullptr, NTOK, 15616, E, V);
}

// Round 12
// 1697.445 us; speedup vs baseline: 1.0117x; 1.0117x over previous
//
#include <hip/hip_runtime.h>
#include <hip/hip_bf16.h>

#define DEPTH 6
#define E 1024
#define H 16
#define S 2048
#define V 32000
#define BB 2
#define HD 64
#define NTOK (BB * S)  // 4096

typedef __attribute__((ext_vector_type(8))) short bf16x8;
typedef __attribute__((ext_vector_type(4))) float f32x4;
typedef unsigned short us;

__device__ inline us f2bf(float f) {
    union { float f; unsigned u; } v; v.f = f;
    unsigned r = v.u + 0x7fff + ((v.u >> 16) & 1);
    return (us)(r >> 16);
}
__device__ inline float bf2f(us b) {
    union { unsigned u; float f; } v; v.u = ((unsigned)b) << 16;
    return v.f;
}

__device__ __forceinline__ void gld16(const us* g, us* l) {
    __builtin_amdgcn_global_load_lds(
        (const __attribute__((address_space(1))) unsigned int*)g,
        (__attribute__((address_space(3))) unsigned int*)l, 16, 0, 0);
}

// ---------------------------------------------------------------- f32 -> bf16 cast (nt-loads: weights read once)
__global__ __launch_bounds__(256) void cast_kernel(const float* __restrict__ in,
                                                   us* __restrict__ out, int n8) {
    int i = blockIdx.x * 256 + threadIdx.x;
    if (i >= n8) return;
    f32x4 a = __builtin_nontemporal_load((const f32x4*)in + 2 * (size_t)i);
    f32x4 b = __builtin_nontemporal_load((const f32x4*)in + 2 * (size_t)i + 1);
    uint4 o;
    o.x = f2bf(a[0]) | ((unsigned)f2bf(a[1]) << 16);
    o.y = f2bf(a[2]) | ((unsigned)f2bf(a[3]) << 16);
    o.z = f2bf(b[0]) | ((unsigned)f2bf(b[1]) << 16);
    o.w = f2bf(b[2]) | ((unsigned)f2bf(b[3]) << 16);
    ((uint4*)out)[i] = o;
}

// ---------------------------------------------------------------- fused embedding + first layernorm
__global__ __launch_bounds__(256) void embed_ln(const int* __restrict__ idx,
                                                const float* __restrict__ tok,
                                                const float* __restrict__ pos,
                                                const float* __restrict__ w,
                                                const float* __restrict__ b,
                                                float* __restrict__ x,
                                                us* __restrict__ out) {
    int t = blockIdx.x;
    int s = t & (S - 1);
    int tokid = idx[t];
    int tid = threadIdx.x;
    int c = tid * 4;
    float4 a = *(const float4*)&tok[(size_t)tokid * E + c];
    float4 p = *(const float4*)&pos[(size_t)s * E + c];
    float4 v; v.x = a.x + p.x; v.y = a.y + p.y; v.z = a.z + p.z; v.w = a.w + p.w;
    *(float4*)&x[(size_t)t * E + c] = v;

    float sum = v.x + v.y + v.z + v.w;
    float sq  = v.x * v.x + v.y * v.y + v.z * v.z + v.w * v.w;
    __shared__ float red[8];
    for (int o = 32; o > 0; o >>= 1) { sum += __shfl_xor(sum, o); sq += __shfl_xor(sq, o); }
    int wave = tid >> 6, lane = tid & 63;
    if (lane == 0) { red[wave] = sum; red[4 + wave] = sq; }
    __syncthreads();
    if (tid == 0) {
        red[0] = red[0] + red[1] + red[2] + red[3];
        red[4] = red[4] + red[5] + red[6] + red[7];
    }
    __syncthreads();
    float mean = red[0] * (1.0f / E);
    float var  = red[4] * (1.0f / E) - mean * mean;
    float rstd = rsqrtf(var + 1e-5f);
    float4 wv = *(const float4*)&w[c];
    float4 bv = *(const float4*)&b[c];
    unsigned a0 = f2bf((v.x - mean) * rstd * wv.x + bv.x);
    unsigned a1 = f2bf((v.y - mean) * rstd * wv.y + bv.y);
    unsigned a2 = f2bf((v.z - mean) * rstd * wv.z + bv.z);
    unsigned a3 = f2bf((v.w - mean) * rstd * wv.w + bv.w);
    uint2 o; o.x = a0 | (a1 << 16); o.y = a2 | (a3 << 16);
    *(uint2*)&out[(size_t)t * E + c] = o;
}

// ---------------------------------------------------------------- layernorm
__global__ __launch_bounds__(256) void ln_kernel(const float* __restrict__ x,
                                                 const float* __restrict__ w,
                                                 const float* __restrict__ b,
                                                 us* __restrict__ out) {
    int row = blockIdx.x;
    int tid = threadIdx.x;
    int c = tid * 4;
    float4 v = *(const float4*)&x[(size_t)row * E + c];
    float s  = v.x + v.y + v.z + v.w;
    float sq = v.x * v.x + v.y * v.y + v.z * v.z + v.w * v.w;
    __shared__ float red[8];
    for (int o = 32; o > 0; o >>= 1) { s += __shfl_xor(s, o); sq += __shfl_xor(sq, o); }
    int wave = tid >> 6, lane = tid & 63;
    if (lane == 0) { red[wave] = s; red[4 + wave] = sq; }
    __syncthreads();
    if (tid == 0) {
        red[0] = red[0] + red[1] + red[2] + red[3];
        red[4] = red[4] + red[5] + red[6] + red[7];
    }
    __syncthreads();
    float mean = red[0] * (1.0f / E);
    float var  = red[4] * (1.0f / E) - mean * mean;
    float rstd = rsqrtf(var + 1e-5f);
    float4 wv = *(const float4*)&w[c];
    float4 bv = *(const float4*)&b[c];
    unsigned a0 = f2bf((v.x - mean) * rstd * wv.x + bv.x);
    unsigned a1 = f2bf((v.y - mean) * rstd * wv.y + bv.y);
    unsigned a2 = f2bf((v.z - mean) * rstd * wv.z + bv.z);
    unsigned a3 = f2bf((v.w - mean) * rstd * wv.w + bv.w);
    uint2 o; o.x = a0 | (a1 << 16); o.y = a2 | (a3 << 16);
    *(uint2*)&out[(size_t)row * E + c] = o;
}

// ---------------------------------------------------------------- fused ff2-combine (4 partials) + layernorm
__global__ __launch_bounds__(256) void combine_ln(const us* __restrict__ p012,
                                                  const us* __restrict__ p3,
                                                  const float* __restrict__ bias,
                                                  float* __restrict__ x,
                                                  const float* __restrict__ w,
                                                  const float* __restrict__ b,
                                                  us* __restrict__ out) {
    int row = blockIdx.x;
    int tid = threadIdx.x;
    int c = tid * 4;
    size_t base = (size_t)row * E + c;
    const size_t stride = (size_t)NTOK * E;
    float4 v = *(const float4*)&x[base];
    uint2 a0 = *(const uint2*)&p012[base];
    uint2 a1 = *(const uint2*)&p012[base + stride];
    uint2 a2 = *(const uint2*)&p012[base + 2 * stride];
    uint2 a3 = *(const uint2*)&p3[base];
    float4 bi = *(const float4*)&bias[c];
    v.x += bf2f((us)(a0.x & 0xffff)) + bf2f((us)(a1.x & 0xffff)) + bf2f((us)(a2.x & 0xffff)) + bf2f((us)(a3.x & 0xffff)) + bi.x;
    v.y += bf2f((us)(a0.x >> 16))    + bf2f((us)(a1.x >> 16))    + bf2f((us)(a2.x >> 16))    + bf2f((us)(a3.x >> 16))    + bi.y;
    v.z += bf2f((us)(a0.y & 0xffff)) + bf2f((us)(a1.y & 0xffff)) + bf2f((us)(a2.y & 0xffff)) + bf2f((us)(a3.y & 0xffff)) + bi.z;
    v.w += bf2f((us)(a0.y >> 16))    + bf2f((us)(a1.y >> 16))    + bf2f((us)(a2.y >> 16))    + bf2f((us)(a3.y >> 16))    + bi.w;
    *(float4*)&x[base] = v;

    float s  = v.x + v.y + v.z + v.w;
    float sq = v.x * v.x + v.y * v.y + v.z * v.z + v.w * v.w;
    __shared__ float red[8];
    for (int o = 32; o > 0; o >>= 1) { s += __shfl_xor(s, o); sq += __shfl_xor(sq, o); }
    int wave = tid >> 6, lane = tid & 63;
    if (lane == 0) { red[wave] = s; red[4 + wave] = sq; }
    __syncthreads();
    if (tid == 0) {
        red[0] = red[0] + red[1] + red[2] + red[3];
        red[4] = red[4] + red[5] + red[6] + red[7];
    }
    __syncthreads();
    float mean = red[0] * (1.0f / E);
    float var  = red[4] * (1.0f / E) - mean * mean;
    float rstd = rsqrtf(var + 1e-5f);
    float4 wv = *(const float4*)&w[c];
    float4 bv = *(const float4*)&b[c];
    unsigned b0 = f2bf((v.x - mean) * rstd * wv.x + bv.x);
    unsigned b1 = f2bf((v.y - mean) * rstd * wv.y + bv.y);
    unsigned b2 = f2bf((v.z - mean) * rstd * wv.z + bv.z);
    unsigned b3 = f2bf((v.w - mean) * rstd * wv.w + bv.w);
    uint2 o; o.x = b0 | (b1 << 16); o.y = b2 | (b3 << 16);
    *(uint2*)&out[base] = o;
}

// ================================================================ 256x256 8-phase GEMM (T2+T3+T4+T5)
// ISVM: 0 = none, 1 = vmcnt(6), 2 = vmcnt(0) (peeled-tail drain)
#define GPH(dd, fb, STAGE, ISVM, IS12)                                              \
  {                                                                                 \
    bf16x8 afr0[2], afr1[2];                                                        \
    if ((fb) == 0) {                                                                \
      _Pragma("unroll")                                                             \
      for (int n = 0; n < 4; n++)                                                   \
        _Pragma("unroll")                                                           \
        for (int ks = 0; ks < 2; ks++)                                              \
          bfr[n][ks] = *(const bf16x8*)&lds[32768 + (dd) * 16384 +                  \
              (brow + n * 16) * 64 + ((ks * 4 + g4) ^ xg) * 8];                     \
    }                                                                               \
    _Pragma("unroll")                                                               \
    for (int ks = 0; ks < 2; ks++) {                                                \
      afr0[ks] = *(const bf16x8*)&lds[(dd) * 16384 + ((fb) >> 1) * 4096 +           \
          arow0 * 64 + ((ks * 4 + g4) ^ xg) * 8];                                   \
      afr1[ks] = *(const bf16x8*)&lds[(dd) * 16384 + ((fb) >> 1) * 4096 +           \
          arow1 * 64 + ((ks * 4 + g4) ^ xg) * 8];                                   \
    }                                                                               \
    STAGE;                                                                          \
    __builtin_amdgcn_sched_barrier(0);                                              \
    if (IS12) asm volatile("s_waitcnt lgkmcnt(8)" ::: "memory");                    \
    __builtin_amdgcn_s_barrier();                                                   \
    asm volatile("s_waitcnt lgkmcnt(0)" ::: "memory");                              \
    __builtin_amdgcn_sched_barrier(0);                                              \
    __builtin_amdgcn_s_setprio(1);                                                  \
    _Pragma("unroll")                                                               \
    for (int n = 0; n < 4; n++)                                                     \
      _Pragma("unroll")                                                             \
      for (int ks = 0; ks < 2; ks++) {                                              \
        acc[(fb)][n]     = __builtin_amdgcn_mfma_f32_16x16x32_bf16(afr0[ks], bfr[n][ks], acc[(fb)][n], 0, 0, 0);     \
        acc[(fb) + 1][n] = __builtin_amdgcn_mfma_f32_16x16x32_bf16(afr1[ks], bfr[n][ks], acc[(fb) + 1][n], 0, 0, 0); \
      }                                                                             \
    __builtin_amdgcn_s_setprio(0);                                                  \
    __builtin_amdgcn_sched_barrier(0);                                              \
    if ((ISVM) == 1) asm volatile("s_waitcnt vmcnt(6)" ::: "memory");               \
    if ((ISVM) == 2) asm volatile("s_waitcnt vmcnt(0)" ::: "memory");               \
    __builtin_amdgcn_s_barrier();                                                   \
  }

// SPLITK=0: sw -> (bm,bn) M-fastest. SPLITK=1: grid = ntile*4, kz chunks of K;
// partial kz<3 -> outp + kz*M*ldo (bf16), kz==3 -> outp3.
// WRITE_VT: qkv mode — V-tiles (bn>=2048, block-uniform) write transposed to vt[b][h][d][s].
template <int OUT_BF16, int ACT_GELU, int HAS_BIAS, int SPLITK, int WRITE_VT>
__global__ __launch_bounds__(512, 2) void gemm256(const us* __restrict__ A, int lda,
                                                  const us* __restrict__ Bw, int ldb,
                                                  const float* __restrict__ bias,
                                                  void* __restrict__ outp,
                                                  void* __restrict__ outp3,
                                                  us* __restrict__ vt,
                                                  int M, int N, int K, int ldo) {
    __shared__ us lds[65536];
    int tid = threadIdx.x;
    int nwg = gridDim.x;
    int wgid = blockIdx.x;
    int chunk = nwg >> 3;
    int sw = (wgid & 7) * chunk + (wgid >> 3);
    int MB = M >> 8;
    int bm, bn;
    us* outb;
    float* outf = (float*)outp;
    if (SPLITK) {
        int ntile = MB * (N >> 8);
        int kz = sw / ntile;
        int rem = sw % ntile;
        bm = (rem % MB) * 256;
        bn = (rem / MB) * 256;
        A  += (size_t)kz * K;
        Bw += (size_t)kz * K;
        outb = (kz < 3) ? (us*)outp + (size_t)kz * M * ldo : (us*)outp3;
    } else {
        bm = (sw % MB) * 256;
        bn = (sw / MB) * 256;
        outb = (us*)outp;
    }
    int w = tid >> 6, lane = tid & 63;
    int wr = w >> 2, wc = w & 3;
    int l15 = lane & 15, g4 = lane >> 4;
    int xg = l15 & 7;
    int arow0 = (wr ? 32 : 0) + l15;
    int arow1 = arow0 + 16;
    int brow = wc * 64 + l15;
    int NT = K >> 6;

    f32x4 acc[8][4] = {};
    bf16x8 bfr[4][2];

    auto stA = [&](int u, int dd, int h) {
        #pragma unroll
        for (int i = 0; i < 2; i++) {
            int k = tid + i * 512;
            int q = 2 * h + (k >> 9);
            int r = (k >> 3) & 63;
            int tr = q * 32 + (r & 31) + ((r >> 5) << 7);
            int gp = (k & 7) ^ (r & 7);
            gld16(A + (size_t)(bm + tr) * lda + u * 64 + gp * 8,
                  &lds[dd * 16384 + h * 8192 + k * 8]);
        }
    };
    auto stB = [&](int u, int dd, int h) {
        #pragma unroll
        for (int i = 0; i < 2; i++) {
            int k = tid + i * 512;
            int row = h * 128 + (k >> 3);
            int gp = (k & 7) ^ ((k >> 3) & 7);
            gld16(Bw + (size_t)(bn + row) * ldb + u * 64 + gp * 8,
                  &lds[32768 + dd * 16384 + h * 8192 + k * 8]);
        }
    };

    stB(0, 0, 0); stB(0, 0, 1); stA(0, 0, 0); stA(0, 0, 1);
    stB(1, 1, 0); stB(1, 1, 1); stA(1, 1, 0);
    __builtin_amdgcn_sched_barrier(0);
    asm volatile("s_waitcnt vmcnt(6)" ::: "memory");
    __builtin_amdgcn_s_barrier();

    #pragma unroll 1
    for (int t = 0; t < NT - 2; t += 2) {
        GPH(0, 0, stA(t + 1, 1, 1), 0, 1)
        GPH(0, 2, stB(t + 2, 0, 0), 0, 0)
        GPH(0, 4, stB(t + 2, 0, 1), 0, 0)
        GPH(0, 6, stA(t + 2, 0, 0), 1, 0)
        GPH(1, 0, stA(t + 2, 0, 1), 0, 1)
        GPH(1, 2, stB(t + 3, 1, 0), 0, 0)
        GPH(1, 4, stB(t + 3, 1, 1), 0, 0)
        GPH(1, 6, stA(t + 3, 1, 0), 1, 0)
    }
    // peeled final iteration (tiles NT-2, NT-1): no beyond-range prefetch.
    GPH(0, 0, stA(NT - 1, 1, 1), 0, 1)
    GPH(0, 2, , 0, 0)
    GPH(0, 4, , 0, 0)
    GPH(0, 6, , 2, 0)
    GPH(1, 0, , 0, 1)
    GPH(1, 2, , 0, 0)
    GPH(1, 4, , 0, 0)
    GPH(1, 6, , 0, 0)

    if (WRITE_VT && bn >= 2048) {
        // V tile: write transposed, packed 4 consecutive s per lane (8B store)
        #pragma unroll
        for (int mf = 0; mf < 8; mf++)
            #pragma unroll
            for (int n = 0; n < 4; n++) {
                int r = bm + wr * 128 + mf * 16 + g4 * 4;
                int c = bn + wc * 64 + n * 16 + l15;
                int hh = (c - 2048) >> 6, d = (c - 2048) & 63;
                int bq = r >> 11, s = r & (S - 1);
                float bv = HAS_BIAS ? bias[c] : 0.0f;
                unsigned o0 = f2bf(acc[mf][n][0] + bv) | ((unsigned)f2bf(acc[mf][n][1] + bv) << 16);
                unsigned o1 = f2bf(acc[mf][n][2] + bv) | ((unsigned)f2bf(acc[mf][n][3] + bv) << 16);
                uint2 pk; pk.x = o0; pk.y = o1;
                *(uint2*)&vt[(((size_t)(bq * H + hh) * 64 + d) << 11) + s] = pk;
            }
        return;
    }
    #pragma unroll
    for (int mf = 0; mf < 8; mf++)
        #pragma unroll
        for (int n = 0; n < 4; n++)
            #pragma unroll
            for (int j = 0; j < 4; j++) {
                int r = bm + wr * 128 + mf * 16 + g4 * 4 + j;
                int c = bn + wc * 64 + n * 16 + l15;
                float v = acc[mf][n][j];
                if (HAS_BIAS) v += bias[c];
                if (ACT_GELU) v = 0.5f * v * (1.0f + erff(v * 0.70710678118f));
                if (OUT_BF16) outb[(size_t)r * ldo + c] = f2bf(v);
                else __builtin_nontemporal_store(v, &outf[(size_t)r * ldo + c]);
            }
}

// ---------------------------------------------------------------- flash attention: 8 waves, QBLK=128, KVB=64
// causal load-balance: b==1 blocks take reversed qt so each CU pairs heavy+light
__global__ __launch_bounds__(512, 4) void attn_kernel(const us* __restrict__ qkv,
                                                      const us* __restrict__ vT,
                                                      float* __restrict__ x) {
    int qt = blockIdx.x, h = blockIdx.y, b = blockIdx.z;
    if (b == 1) qt = (S / 128 - 1) - qt;   // heavy+light pairing per CU
    int tid = threadIdx.x;
    int w = tid >> 6, lane = tid & 63;
    int l15 = lane & 15, g4 = lane >> 4;
    int s0 = qt * 128;
    int qrow_base = s0 + w * 16;
    const size_t qbase = (size_t)b * S * 3072;
    const size_t vtbase = ((size_t)(b * H + h) * 64) * S;

    __shared__ us K_lds[2][64 * 64];
    __shared__ us VT_lds[2][64 * 64];
    __shared__ us P_lds[8][16 * 72];

    bf16x8 q[2];
    #pragma unroll
    for (int dc = 0; dc < 2; dc++) {
        q[dc] = *(const bf16x8*)&qkv[qbase + (size_t)(qrow_base + l15) * 3072 + h * 64 + dc * 32 + 8 * g4];
        us* qq = (us*)&q[dc];
        #pragma unroll
        for (int e = 0; e < 8; e++) qq[e] = f2bf(bf2f(qq[e]) * 0.125f);  // fold 1/sqrt(d)
    }

    f32x4 O[4] = {};
    float m_run[4], l_part[4];
    #pragma unroll
    for (int j = 0; j < 4; j++) { m_run[j] = -INFINITY; l_part[j] = 0.0f; }

    int lastt = 2 * qt + 1;
    {
        int p = tid, row = p >> 3, cc = p & 7;
        int scc = cc ^ (row & 7);
        gld16(&qkv[qbase + (size_t)(0 + row) * 3072 + 1024 + h * 64 + scc * 8], &K_lds[0][p * 8]);
        gld16(&vT[vtbase + (size_t)row * S + 0 + scc * 8], &VT_lds[0][p * 8]);
    }
    __syncthreads();

    for (int t = 0; t <= lastt; t++) {
        int bb = t & 1;
        if (t < lastt) {
            int p = tid, row = p >> 3, cc = p & 7;
            int scc = cc ^ (row & 7);
            gld16(&qkv[qbase + (size_t)((t + 1) * 64 + row) * 3072 + 1024 + h * 64 + scc * 8], &K_lds[bb ^ 1][p * 8]);
            gld16(&vT[vtbase + (size_t)row * S + (t + 1) * 64 + scc * 8], &VT_lds[bb ^ 1][p * 8]);
        }
        int k0 = t * 64;
        if (k0 <= qrow_base + 15) {
            f32x4 sf[4];
            __builtin_amdgcn_s_setprio(1);
            #pragma unroll
            for (int c = 0; c < 4; c++) {
                f32x4 z = {};
                int row = c * 16 + l15;
                #pragma unroll
                for (int dc = 0; dc < 2; dc++) {
                    int ch = (dc * 4 + g4) ^ (row & 7);
                    bf16x8 kb = *(const bf16x8*)&K_lds[bb][row * 64 + ch * 8];
                    z = __builtin_amdgcn_mfma_f32_16x16x32_bf16(q[dc], kb, z, 0, 0, 0);
                }
                sf[c] = z;
            }
            __builtin_amdgcn_s_setprio(0);
            bool needmask = (k0 + 63 > qrow_base);
            float vv[4][4], tmr[4];
            #pragma unroll
            for (int j = 0; j < 4; j++) {
                int qrow = qrow_base + g4 * 4 + j;
                float v0 = sf[0][j], v1 = sf[1][j];
                float v2 = sf[2][j], v3 = sf[3][j];
                if (needmask) {
                    if (k0 +      l15 > qrow) v0 = -INFINITY;
                    if (k0 + 16 + l15 > qrow) v1 = -INFINITY;
                    if (k0 + 32 + l15 > qrow) v2 = -INFINITY;
                    if (k0 + 48 + l15 > qrow) v3 = -INFINITY;
                }
                float tm = fmaxf(fmaxf(v0, v1), fmaxf(v2, v3));
                tm = fmaxf(tm, __shfl_xor(tm, 1, 16));
                tm = fmaxf(tm, __shfl_xor(tm, 2, 16));
                tm = fmaxf(tm, __shfl_xor(tm, 4, 16));
                tm = fmaxf(tm, __shfl_xor(tm, 8, 16));
                tmr[j] = tm;
                vv[0][j] = v0; vv[1][j] = v1; vv[2][j] = v2; vv[3][j] = v3;
            }
            bool grow = (tmr[0] > m_run[0] + 8.0f) || (tmr[1] > m_run[1] + 8.0f) ||
                        (tmr[2] > m_run[2] + 8.0f) || (tmr[3] > m_run[3] + 8.0f);
            bool skip = !__any(grow);
            float pr[4][4], alpha[4];
            #pragma unroll
            for (int j = 0; j < 4; j++) {
                float mnew = skip ? m_run[j] : fmaxf(m_run[j], tmr[j]);
                float p0 = __expf(vv[0][j] - mnew), p1 = __expf(vv[1][j] - mnew);
                float p2 = __expf(vv[2][j] - mnew), p3 = __expf(vv[3][j] - mnew);
                float sum4 = (p0 + p1) + (p2 + p3);
                if (skip) {
                    l_part[j] += sum4;
                } else {
                    alpha[j] = __expf(m_run[j] - mnew);
                    l_part[j] = l_part[j] * alpha[j] + sum4;
                    m_run[j] = mnew;
                }
                pr[0][j] = p0; pr[1][j] = p1; pr[2][j] = p2; pr[3][j] = p3;
            }
            if (!skip) {
                #pragma unroll
                for (int f = 0; f < 4; f++)
                    #pragma unroll
                    for (int j = 0; j < 4; j++) O[f][j] *= alpha[j];
            }
            us* Pw = &P_lds[w][0];
            #pragma unroll
            for (int c = 0; c < 4; c++)
                #pragma unroll
                for (int j = 0; j < 4; j++)
                    Pw[(g4 * 4 + j) * 72 + c * 16 + l15] = f2bf(pr[c][j]);
            __builtin_amdgcn_s_setprio(1);
            #pragma unroll
            for (int kc = 0; kc < 2; kc++) {
                bf16x8 pa = *(const bf16x8*)&Pw[l15 * 72 + kc * 32 + g4 * 8];
                #pragma unroll
                for (int dt = 0; dt < 4; dt++) {
                    int row = dt * 16 + l15;
                    int ch = (kc * 4 + g4) ^ (row & 7);
                    bf16x8 vb = *(const bf16x8*)&VT_lds[bb][row * 64 + ch * 8];
                    O[dt] = __builtin_amdgcn_mfma_f32_16x16x32_bf16(pa, vb, O[dt], 0, 0, 0);
                }
            }
            __builtin_amdgcn_s_setprio(0);
        }
        __syncthreads();
    }
    float l_run[4];
    #pragma unroll
    for (int j = 0; j < 4; j++) {
        float l = l_part[j];
        l += __shfl_xor(l, 1, 16);
        l += __shfl_xor(l, 2, 16);
        l += __shfl_xor(l, 4, 16);
        l += __shfl_xor(l, 8, 16);
        l_run[j] = l;
    }
    #pragma unroll
    for (int dt = 0; dt < 4; dt++)
        #pragma unroll
        for (int j = 0; j < 4; j++) {
            size_t o = ((size_t)b * S + qrow_base + g4 * 4 + j) * E + h * 64 + dt * 16 + l15;
            x[o] += O[dt][j] / l_run[j];
        }
}

// ---------------------------------------------------------------- launch
extern "C" void kernel_launch(void* const* d_in, const int* in_sizes, int n_in,
                              void* d_out, int out_size, void* d_ws, size_t ws_size,
                              hipStream_t stream) {
    const int*   idx    = (const int*)d_in[0];
    const float* tok    = (const float*)d_in[1];
    const float* pos    = (const float*)d_in[2];
    const float* qkv_w  = (const float*)d_in[3];
    const float* qkv_b  = (const float*)d_in[4];
    const float* ln1_w  = (const float*)d_in[5];
    const float* ln1_b  = (const float*)d_in[6];
    const float* ln2_w  = (const float*)d_in[7];
    const float* ln2_b  = (const float*)d_in[8];
    const float* ff1_w  = (const float*)d_in[9];
    const float* ff1_b  = (const float*)d_in[10];
    const float* ff2_w  = (const float*)d_in[11];
    const float* ff2_b  = (const float*)d_in[12];
    const float* fin_w  = (const float*)d_in[13];
    const float* fin_b  = (const float*)d_in[14];
    const float* proj_w = (const float*)d_in[15];

    char* ws = (char*)d_ws;
    float* x    = (float*)ws;                          // 16.78 MB f32 residual
    us*    xn   = (us*)(ws + 16777216);                // 8.39 MB bf16 LN out
    us*    qkvb = (us*)(ws + 25165824);                // 25.17 MB bf16 qkv / ff2 partials 0-2
    us*    hbuf = (us*)(ws + 50331648);                // 33.55 MB bf16 ff hidden
    us*    wbuf = (us*)(ws + 83886080);                // 8.39 MB bf16 per-layer weights
    us*    vTb  = (us*)(ws + 92274688);                // 8.39 MB bf16 V^T / ff2 partial 3
    us*    pbuf = qkvb;                                // 65.5 MB proj weights (qkvb..wbuf span, free then)

    embed_ln<<<NTOK, 256, 0, stream>>>(idx, tok, pos, ln1_w, ln1_b, x, xn);
    for (int l = 0; l < DEPTH; l++) {
        cast_kernel<<<1536, 256, 0, stream>>>(qkv_w + (size_t)l * 3 * E * E, wbuf, 3 * E * E / 8);
        // qkv: Q,K rows to qkvb; V written transposed to vTb in-epilogue
        gemm256<1, 0, 1, 0, 1><<<192, 512, 0, stream>>>(
            xn, E, wbuf, E, qkv_b + l * 3 * E, qkvb, nullptr, vTb, NTOK, 3 * E, E, 3 * E);
        attn_kernel<<<dim3(S / 128, H, BB), 512, 0, stream>>>(qkvb, vTb, x);
        ln_kernel<<<NTOK, 256, 0, stream>>>(x, ln2_w + l * E, ln2_b + l * E, xn);
        cast_kernel<<<2048, 256, 0, stream>>>(ff1_w + (size_t)l * 4 * E * E, wbuf, 4 * E * E / 8);
        gemm256<1, 1, 1, 0, 0><<<256, 512, 0, stream>>>(
            xn, E, wbuf, E, ff1_b + l * 4 * E, hbuf, nullptr, nullptr, NTOK, 4 * E, E, 4 * E);
        cast_kernel<<<2048, 256, 0, stream>>>(ff2_w + (size_t)l * E * 4 * E, wbuf, 4 * E * E / 8);
        // ff2: 256^2 8-phase split-K x4 (grid 256 = 1 block/CU), bf16 partials
        gemm256<1, 0, 0, 1, 0><<<256, 512, 0, stream>>>(
            hbuf, 4 * E, wbuf, 4 * E, nullptr, qkvb, vTb, nullptr, NTOK, E, E, E);
        const float* nw = (l < DEPTH - 1) ? (ln1_w + (l + 1) * E) : fin_w;
        const float* nb = (l < DEPTH - 1) ? (ln1_b + (l + 1) * E) : fin_b;
        combine_ln<<<NTOK, 256, 0, stream>>>(qkvb, vTb, ff2_b + l * E, x, nw, nb, xn);
    }
    cast_kernel<<<16000, 256, 0, stream>>>(proj_w, pbuf, V * E / 8);
    gemm256<0, 0, 0, 0, 0><<<2000, 512, 0, stream>>>(
        xn, E, pbuf, E, nullptr, d_out, nullptr, nullptr, NTOK, V, E, V);
}

// Round 13
// 1695.365 us; speedup vs baseline: 1.0129x; 1.0012x over previous
//
#include <hip/hip_runtime.h>
#include <hip/hip_bf16.h>

#define DEPTH 6
#define E 1024
#define H 16
#define S 2048
#define V 32000
#define BB 2
#define HD 64
#define NTOK (BB * S)  // 4096

typedef __attribute__((ext_vector_type(8))) short bf16x8;
typedef __attribute__((ext_vector_type(4))) float f32x4;
typedef unsigned short us;

__device__ inline us f2bf(float f) {
    union { float f; unsigned u; } v; v.f = f;
    unsigned r = v.u + 0x7fff + ((v.u >> 16) & 1);
    return (us)(r >> 16);
}
__device__ inline float bf2f(us b) {
    union { unsigned u; float f; } v; v.u = ((unsigned)b) << 16;
    return v.f;
}

__device__ __forceinline__ void gld16(const us* g, us* l) {
    __builtin_amdgcn_global_load_lds(
        (const __attribute__((address_space(1))) unsigned int*)g,
        (__attribute__((address_space(3))) unsigned int*)l, 16, 0, 0);
}

// ---------------------------------------------------------------- f32 -> bf16 cast (nt-loads: weights read once)
__global__ __launch_bounds__(256) void cast_kernel(const float* __restrict__ in,
                                                   us* __restrict__ out, int n8) {
    int i = blockIdx.x * 256 + threadIdx.x;
    if (i >= n8) return;
    f32x4 a = __builtin_nontemporal_load((const f32x4*)in + 2 * (size_t)i);
    f32x4 b = __builtin_nontemporal_load((const f32x4*)in + 2 * (size_t)i + 1);
    uint4 o;
    o.x = f2bf(a[0]) | ((unsigned)f2bf(a[1]) << 16);
    o.y = f2bf(a[2]) | ((unsigned)f2bf(a[3]) << 16);
    o.z = f2bf(b[0]) | ((unsigned)f2bf(b[1]) << 16);
    o.w = f2bf(b[2]) | ((unsigned)f2bf(b[3]) << 16);
    ((uint4*)out)[i] = o;
}

// ---------------------------------------------------------------- fused embedding + first layernorm
__global__ __launch_bounds__(256) void embed_ln(const int* __restrict__ idx,
                                                const float* __restrict__ tok,
                                                const float* __restrict__ pos,
                                                const float* __restrict__ w,
                                                const float* __restrict__ b,
                                                float* __restrict__ x,
                                                us* __restrict__ out) {
    int t = blockIdx.x;
    int s = t & (S - 1);
    int tokid = idx[t];
    int tid = threadIdx.x;
    int c = tid * 4;
    float4 a = *(const float4*)&tok[(size_t)tokid * E + c];
    float4 p = *(const float4*)&pos[(size_t)s * E + c];
    float4 v; v.x = a.x + p.x; v.y = a.y + p.y; v.z = a.z + p.z; v.w = a.w + p.w;
    *(float4*)&x[(size_t)t * E + c] = v;

    float sum = v.x + v.y + v.z + v.w;
    float sq  = v.x * v.x + v.y * v.y + v.z * v.z + v.w * v.w;
    __shared__ float red[8];
    for (int o = 32; o > 0; o >>= 1) { sum += __shfl_xor(sum, o); sq += __shfl_xor(sq, o); }
    int wave = tid >> 6, lane = tid & 63;
    if (lane == 0) { red[wave] = sum; red[4 + wave] = sq; }
    __syncthreads();
    if (tid == 0) {
        red[0] = red[0] + red[1] + red[2] + red[3];
        red[4] = red[4] + red[5] + red[6] + red[7];
    }
    __syncthreads();
    float mean = red[0] * (1.0f / E);
    float var  = red[4] * (1.0f / E) - mean * mean;
    float rstd = rsqrtf(var + 1e-5f);
    float4 wv = *(const float4*)&w[c];
    float4 bv = *(const float4*)&b[c];
    unsigned a0 = f2bf((v.x - mean) * rstd * wv.x + bv.x);
    unsigned a1 = f2bf((v.y - mean) * rstd * wv.y + bv.y);
    unsigned a2 = f2bf((v.z - mean) * rstd * wv.z + bv.z);
    unsigned a3 = f2bf((v.w - mean) * rstd * wv.w + bv.w);
    uint2 o; o.x = a0 | (a1 << 16); o.y = a2 | (a3 << 16);
    *(uint2*)&out[(size_t)t * E + c] = o;
}

// ---------------------------------------------------------------- layernorm
__global__ __launch_bounds__(256) void ln_kernel(const float* __restrict__ x,
                                                 const float* __restrict__ w,
                                                 const float* __restrict__ b,
                                                 us* __restrict__ out) {
    int row = blockIdx.x;
    int tid = threadIdx.x;
    int c = tid * 4;
    float4 v = *(const float4*)&x[(size_t)row * E + c];
    float s  = v.x + v.y + v.z + v.w;
    float sq = v.x * v.x + v.y * v.y + v.z * v.z + v.w * v.w;
    __shared__ float red[8];
    for (int o = 32; o > 0; o >>= 1) { s += __shfl_xor(s, o); sq += __shfl_xor(sq, o); }
    int wave = tid >> 6, lane = tid & 63;
    if (lane == 0) { red[wave] = s; red[4 + wave] = sq; }
    __syncthreads();
    if (tid == 0) {
        red[0] = red[0] + red[1] + red[2] + red[3];
        red[4] = red[4] + red[5] + red[6] + red[7];
    }
    __syncthreads();
    float mean = red[0] * (1.0f / E);
    float var  = red[4] * (1.0f / E) - mean * mean;
    float rstd = rsqrtf(var + 1e-5f);
    float4 wv = *(const float4*)&w[c];
    float4 bv = *(const float4*)&b[c];
    unsigned a0 = f2bf((v.x - mean) * rstd * wv.x + bv.x);
    unsigned a1 = f2bf((v.y - mean) * rstd * wv.y + bv.y);
    unsigned a2 = f2bf((v.z - mean) * rstd * wv.z + bv.z);
    unsigned a3 = f2bf((v.w - mean) * rstd * wv.w + bv.w);
    uint2 o; o.x = a0 | (a1 << 16); o.y = a2 | (a3 << 16);
    *(uint2*)&out[(size_t)row * E + c] = o;
}

// ---------------------------------------------------------------- fused ff2-combine (4 partials) + layernorm
__global__ __launch_bounds__(256) void combine_ln(const us* __restrict__ p012,
                                                  const us* __restrict__ p3,
                                                  const float* __restrict__ bias,
                                                  float* __restrict__ x,
                                                  const float* __restrict__ w,
                                                  const float* __restrict__ b,
                                                  us* __restrict__ out) {
    int row = blockIdx.x;
    int tid = threadIdx.x;
    int c = tid * 4;
    size_t base = (size_t)row * E + c;
    const size_t stride = (size_t)NTOK * E;
    float4 v = *(const float4*)&x[base];
    uint2 a0 = *(const uint2*)&p012[base];
    uint2 a1 = *(const uint2*)&p012[base + stride];
    uint2 a2 = *(const uint2*)&p012[base + 2 * stride];
    uint2 a3 = *(const uint2*)&p3[base];
    float4 bi = *(const float4*)&bias[c];
    v.x += bf2f((us)(a0.x & 0xffff)) + bf2f((us)(a1.x & 0xffff)) + bf2f((us)(a2.x & 0xffff)) + bf2f((us)(a3.x & 0xffff)) + bi.x;
    v.y += bf2f((us)(a0.x >> 16))    + bf2f((us)(a1.x >> 16))    + bf2f((us)(a2.x >> 16))    + bf2f((us)(a3.x >> 16))    + bi.y;
    v.z += bf2f((us)(a0.y & 0xffff)) + bf2f((us)(a1.y & 0xffff)) + bf2f((us)(a2.y & 0xffff)) + bf2f((us)(a3.y & 0xffff)) + bi.z;
    v.w += bf2f((us)(a0.y >> 16))    + bf2f((us)(a1.y >> 16))    + bf2f((us)(a2.y >> 16))    + bf2f((us)(a3.y >> 16))    + bi.w;
    *(float4*)&x[base] = v;

    float s  = v.x + v.y + v.z + v.w;
    float sq = v.x * v.x + v.y * v.y + v.z * v.z + v.w * v.w;
    __shared__ float red[8];
    for (int o = 32; o > 0; o >>= 1) { s += __shfl_xor(s, o); sq += __shfl_xor(sq, o); }
    int wave = tid >> 6, lane = tid & 63;
    if (lane == 0) { red[wave] = s; red[4 + wave] = sq; }
    __syncthreads();
    if (tid == 0) {
        red[0] = red[0] + red[1] + red[2] + red[3];
        red[4] = red[4] + red[5] + red[6] + red[7];
    }
    __syncthreads();
    float mean = red[0] * (1.0f / E);
    float var  = red[4] * (1.0f / E) - mean * mean;
    float rstd = rsqrtf(var + 1e-5f);
    float4 wv = *(const float4*)&w[c];
    float4 bv = *(const float4*)&b[c];
    unsigned b0 = f2bf((v.x - mean) * rstd * wv.x + bv.x);
    unsigned b1 = f2bf((v.y - mean) * rstd * wv.y + bv.y);
    unsigned b2 = f2bf((v.z - mean) * rstd * wv.z + bv.z);
    unsigned b3 = f2bf((v.w - mean) * rstd * wv.w + bv.w);
    uint2 o; o.x = b0 | (b1 << 16); o.y = b2 | (b3 << 16);
    *(uint2*)&out[base] = o;
}

// ================================================================ 256x256 8-phase GEMM (T2+T3+T4+T5)
// ISVM: 0 = none, 1 = vmcnt(6), 2 = vmcnt(0) (peeled-tail drain)
#define GPH(dd, fb, STAGE, ISVM, IS12)                                              \
  {                                                                                 \
    bf16x8 afr0[2], afr1[2];                                                        \
    if ((fb) == 0) {                                                                \
      _Pragma("unroll")                                                             \
      for (int n = 0; n < 4; n++)                                                   \
        _Pragma("unroll")                                                           \
        for (int ks = 0; ks < 2; ks++)                                              \
          bfr[n][ks] = *(const bf16x8*)&lds[32768 + (dd) * 16384 +                  \
              (brow + n * 16) * 64 + ((ks * 4 + g4) ^ xg) * 8];                     \
    }                                                                               \
    _Pragma("unroll")                                                               \
    for (int ks = 0; ks < 2; ks++) {                                                \
      afr0[ks] = *(const bf16x8*)&lds[(dd) * 16384 + ((fb) >> 1) * 4096 +           \
          arow0 * 64 + ((ks * 4 + g4) ^ xg) * 8];                                   \
      afr1[ks] = *(const bf16x8*)&lds[(dd) * 16384 + ((fb) >> 1) * 4096 +           \
          arow1 * 64 + ((ks * 4 + g4) ^ xg) * 8];                                   \
    }                                                                               \
    STAGE;                                                                          \
    __builtin_amdgcn_sched_barrier(0);                                              \
    if (IS12) asm volatile("s_waitcnt lgkmcnt(8)" ::: "memory");                    \
    __builtin_amdgcn_s_barrier();                                                   \
    asm volatile("s_waitcnt lgkmcnt(0)" ::: "memory");                              \
    __builtin_amdgcn_sched_barrier(0);                                              \
    __builtin_amdgcn_s_setprio(1);                                                  \
    _Pragma("unroll")                                                               \
    for (int n = 0; n < 4; n++)                                                     \
      _Pragma("unroll")                                                             \
      for (int ks = 0; ks < 2; ks++) {                                              \
        acc[(fb)][n]     = __builtin_amdgcn_mfma_f32_16x16x32_bf16(afr0[ks], bfr[n][ks], acc[(fb)][n], 0, 0, 0);     \
        acc[(fb) + 1][n] = __builtin_amdgcn_mfma_f32_16x16x32_bf16(afr1[ks], bfr[n][ks], acc[(fb) + 1][n], 0, 0, 0); \
      }                                                                             \
    __builtin_amdgcn_s_setprio(0);                                                  \
    __builtin_amdgcn_sched_barrier(0);                                              \
    if ((ISVM) == 1) asm volatile("s_waitcnt vmcnt(6)" ::: "memory");               \
    if ((ISVM) == 2) asm volatile("s_waitcnt vmcnt(0)" ::: "memory");               \
    __builtin_amdgcn_s_barrier();                                                   \
  }

// SPLITK=0: sw -> (bm,bn) M-fastest over gemm_nwg blocks. SPLITK=1: kz chunks of K.
// WRITE_VT: qkv mode — V-tiles (bn>=2048) write transposed to vt[b][h][d][s].
// RIDER: blocks with wgid >= gemm_nwg grid-stride cast csrc(f32) -> cdst(bf16)
//        with row length 128 octets mapped to dst rows of dst_ld elems (dst_ld=1024 => flat).
template <int OUT_BF16, int ACT_GELU, int HAS_BIAS, int SPLITK, int WRITE_VT, int RIDER>
__global__ __launch_bounds__(512, 2) void gemm256(const us* __restrict__ A, int lda,
                                                  const us* __restrict__ Bw, int ldb,
                                                  const float* __restrict__ bias,
                                                  void* __restrict__ outp,
                                                  void* __restrict__ outp3,
                                                  us* __restrict__ vt,
                                                  const float* __restrict__ csrc,
                                                  us* __restrict__ cdst,
                                                  int dst_ld, int gemm_nwg,
                                                  int M, int N, int K, int ldo) {
    int tid = threadIdx.x;
    int wgid = blockIdx.x;
    if (RIDER && wgid >= gemm_nwg) {
        int nrb = gridDim.x - gemm_nwg;
        int rtid = (wgid - gemm_nwg) * 512 + tid;
        int nthr = nrb * 512;
        for (int j = rtid; j < 4 * E * E / 8; j += nthr) {
            f32x4 a = __builtin_nontemporal_load((const f32x4*)csrc + 2 * (size_t)j);
            f32x4 b = __builtin_nontemporal_load((const f32x4*)csrc + 2 * (size_t)j + 1);
            uint4 o;
            o.x = f2bf(a[0]) | ((unsigned)f2bf(a[1]) << 16);
            o.y = f2bf(a[2]) | ((unsigned)f2bf(a[3]) << 16);
            o.z = f2bf(b[0]) | ((unsigned)f2bf(b[1]) << 16);
            o.w = f2bf(b[2]) | ((unsigned)f2bf(b[3]) << 16);
            int n = j >> 7, c8 = (j & 127) << 3;
            *(uint4*)&cdst[(size_t)n * dst_ld + c8] = o;
        }
        return;
    }
    __shared__ us lds[65536];
    int chunk = gemm_nwg >> 3;
    int sw = (wgid & 7) * chunk + (wgid >> 3);
    int MB = M >> 8;
    int bm, bn;
    us* outb;
    float* outf = (float*)outp;
    if (SPLITK) {
        int ntile = MB * (N >> 8);
        int kz = sw / ntile;
        int rem = sw % ntile;
        bm = (rem % MB) * 256;
        bn = (rem / MB) * 256;
        A  += (size_t)kz * K;
        Bw += (size_t)kz * K;
        outb = (kz < 3) ? (us*)outp + (size_t)kz * M * ldo : (us*)outp3;
    } else {
        bm = (sw % MB) * 256;
        bn = (sw / MB) * 256;
        outb = (us*)outp;
    }
    int w = tid >> 6, lane = tid & 63;
    int wr = w >> 2, wc = w & 3;
    int l15 = lane & 15, g4 = lane >> 4;
    int xg = l15 & 7;
    int arow0 = (wr ? 32 : 0) + l15;
    int arow1 = arow0 + 16;
    int brow = wc * 64 + l15;
    int NT = K >> 6;

    f32x4 acc[8][4] = {};
    bf16x8 bfr[4][2];

    auto stA = [&](int u, int dd, int h) {
        #pragma unroll
        for (int i = 0; i < 2; i++) {
            int k = tid + i * 512;
            int q = 2 * h + (k >> 9);
            int r = (k >> 3) & 63;
            int tr = q * 32 + (r & 31) + ((r >> 5) << 7);
            int gp = (k & 7) ^ (r & 7);
            gld16(A + (size_t)(bm + tr) * lda + u * 64 + gp * 8,
                  &lds[dd * 16384 + h * 8192 + k * 8]);
        }
    };
    auto stB = [&](int u, int dd, int h) {
        #pragma unroll
        for (int i = 0; i < 2; i++) {
            int k = tid + i * 512;
            int row = h * 128 + (k >> 3);
            int gp = (k & 7) ^ ((k >> 3) & 7);
            gld16(Bw + (size_t)(bn + row) * ldb + u * 64 + gp * 8,
                  &lds[32768 + dd * 16384 + h * 8192 + k * 8]);
        }
    };

    stB(0, 0, 0); stB(0, 0, 1); stA(0, 0, 0); stA(0, 0, 1);
    stB(1, 1, 0); stB(1, 1, 1); stA(1, 1, 0);
    __builtin_amdgcn_sched_barrier(0);
    asm volatile("s_waitcnt vmcnt(6)" ::: "memory");
    __builtin_amdgcn_s_barrier();

    #pragma unroll 1
    for (int t = 0; t < NT - 2; t += 2) {
        GPH(0, 0, stA(t + 1, 1, 1), 0, 1)
        GPH(0, 2, stB(t + 2, 0, 0), 0, 0)
        GPH(0, 4, stB(t + 2, 0, 1), 0, 0)
        GPH(0, 6, stA(t + 2, 0, 0), 1, 0)
        GPH(1, 0, stA(t + 2, 0, 1), 0, 1)
        GPH(1, 2, stB(t + 3, 1, 0), 0, 0)
        GPH(1, 4, stB(t + 3, 1, 1), 0, 0)
        GPH(1, 6, stA(t + 3, 1, 0), 1, 0)
    }
    // peeled final iteration (tiles NT-2, NT-1): no beyond-range prefetch.
    GPH(0, 0, stA(NT - 1, 1, 1), 0, 1)
    GPH(0, 2, , 0, 0)
    GPH(0, 4, , 0, 0)
    GPH(0, 6, , 2, 0)
    GPH(1, 0, , 0, 1)
    GPH(1, 2, , 0, 0)
    GPH(1, 4, , 0, 0)
    GPH(1, 6, , 0, 0)

    if (WRITE_VT && bn >= 2048) {
        // V tile: write transposed, packed 4 consecutive s per lane (8B store)
        #pragma unroll
        for (int mf = 0; mf < 8; mf++)
            #pragma unroll
            for (int n = 0; n < 4; n++) {
                int r = bm + wr * 128 + mf * 16 + g4 * 4;
                int c = bn + wc * 64 + n * 16 + l15;
                int hh = (c - 2048) >> 6, d = (c - 2048) & 63;
                int bq = r >> 11, s = r & (S - 1);
                float bv = HAS_BIAS ? bias[c] : 0.0f;
                unsigned o0 = f2bf(acc[mf][n][0] + bv) | ((unsigned)f2bf(acc[mf][n][1] + bv) << 16);
                unsigned o1 = f2bf(acc[mf][n][2] + bv) | ((unsigned)f2bf(acc[mf][n][3] + bv) << 16);
                uint2 pk; pk.x = o0; pk.y = o1;
                *(uint2*)&vt[(((size_t)(bq * H + hh) * 64 + d) << 11) + s] = pk;
            }
        return;
    }
    #pragma unroll
    for (int mf = 0; mf < 8; mf++)
        #pragma unroll
        for (int n = 0; n < 4; n++)
            #pragma unroll
            for (int j = 0; j < 4; j++) {
                int r = bm + wr * 128 + mf * 16 + g4 * 4 + j;
                int c = bn + wc * 64 + n * 16 + l15;
                float v = acc[mf][n][j];
                if (HAS_BIAS) v += bias[c];
                if (ACT_GELU) v = 0.5f * v * (1.0f + erff(v * 0.70710678118f));
                if (OUT_BF16) outb[(size_t)r * ldo + c] = f2bf(v);
                else __builtin_nontemporal_store(v, &outf[(size_t)r * ldo + c]);
            }
}

// ---------------------------------------------------------------- flash attention: 8 waves, QBLK=128, KVB=64
// causal load-balance: b==1 blocks take reversed qt so each CU pairs heavy+light
__global__ __launch_bounds__(512, 4) void attn_kernel(const us* __restrict__ qkv,
                                                      const us* __restrict__ vT,
                                                      float* __restrict__ x) {
    int qt = blockIdx.x, h = blockIdx.y, b = blockIdx.z;
    if (b == 1) qt = (S / 128 - 1) - qt;   // heavy+light pairing per CU
    int tid = threadIdx.x;
    int w = tid >> 6, lane = tid & 63;
    int l15 = lane & 15, g4 = lane >> 4;
    int s0 = qt * 128;
    int qrow_base = s0 + w * 16;
    const size_t qbase = (size_t)b * S * 3072;
    const size_t vtbase = ((size_t)(b * H + h) * 64) * S;

    __shared__ us K_lds[2][64 * 64];
    __shared__ us VT_lds[2][64 * 64];
    __shared__ us P_lds[8][16 * 72];

    bf16x8 q[2];
    #pragma unroll
    for (int dc = 0; dc < 2; dc++) {
        q[dc] = *(const bf16x8*)&qkv[qbase + (size_t)(qrow_base + l15) * 3072 + h * 64 + dc * 32 + 8 * g4];
        us* qq = (us*)&q[dc];
        #pragma unroll
        for (int e = 0; e < 8; e++) qq[e] = f2bf(bf2f(qq[e]) * 0.125f);  // fold 1/sqrt(d)
    }

    f32x4 O[4] = {};
    float m_run[4], l_part[4];
    #pragma unroll
    for (int j = 0; j < 4; j++) { m_run[j] = -INFINITY; l_part[j] = 0.0f; }

    int lastt = 2 * qt + 1;
    {
        int p = tid, row = p >> 3, cc = p & 7;
        int scc = cc ^ (row & 7);
        gld16(&qkv[qbase + (size_t)(0 + row) * 3072 + 1024 + h * 64 + scc * 8], &K_lds[0][p * 8]);
        gld16(&vT[vtbase + (size_t)row * S + 0 + scc * 8], &VT_lds[0][p * 8]);
    }
    __syncthreads();

    for (int t = 0; t <= lastt; t++) {
        int bb = t & 1;
        if (t < lastt) {
            int p = tid, row = p >> 3, cc = p & 7;
            int scc = cc ^ (row & 7);
            gld16(&qkv[qbase + (size_t)((t + 1) * 64 + row) * 3072 + 1024 + h * 64 + scc * 8], &K_lds[bb ^ 1][p * 8]);
            gld16(&vT[vtbase + (size_t)row * S + (t + 1) * 64 + scc * 8], &VT_lds[bb ^ 1][p * 8]);
        }
        int k0 = t * 64;
        if (k0 <= qrow_base + 15) {
            f32x4 sf[4];
            __builtin_amdgcn_s_setprio(1);
            #pragma unroll
            for (int c = 0; c < 4; c++) {
                f32x4 z = {};
                int row = c * 16 + l15;
                #pragma unroll
                for (int dc = 0; dc < 2; dc++) {
                    int ch = (dc * 4 + g4) ^ (row & 7);
                    bf16x8 kb = *(const bf16x8*)&K_lds[bb][row * 64 + ch * 8];
                    z = __builtin_amdgcn_mfma_f32_16x16x32_bf16(q[dc], kb, z, 0, 0, 0);
                }
                sf[c] = z;
            }
            __builtin_amdgcn_s_setprio(0);
            bool needmask = (k0 + 63 > qrow_base);
            float vv[4][4], tmr[4];
            #pragma unroll
            for (int j = 0; j < 4; j++) {
                int qrow = qrow_base + g4 * 4 + j;
                float v0 = sf[0][j], v1 = sf[1][j];
                float v2 = sf[2][j], v3 = sf[3][j];
                if (needmask) {
                    if (k0 +      l15 > qrow) v0 = -INFINITY;
                    if (k0 + 16 + l15 > qrow) v1 = -INFINITY;
                    if (k0 + 32 + l15 > qrow) v2 = -INFINITY;
                    if (k0 + 48 + l15 > qrow) v3 = -INFINITY;
                }
                float tm = fmaxf(fmaxf(v0, v1), fmaxf(v2, v3));
                tm = fmaxf(tm, __shfl_xor(tm, 1, 16));
                tm = fmaxf(tm, __shfl_xor(tm, 2, 16));
                tm = fmaxf(tm, __shfl_xor(tm, 4, 16));
                tm = fmaxf(tm, __shfl_xor(tm, 8, 16));
                tmr[j] = tm;
                vv[0][j] = v0; vv[1][j] = v1; vv[2][j] = v2; vv[3][j] = v3;
            }
            bool grow = (tmr[0] > m_run[0] + 8.0f) || (tmr[1] > m_run[1] + 8.0f) ||
                        (tmr[2] > m_run[2] + 8.0f) || (tmr[3] > m_run[3] + 8.0f);
            bool skip = !__any(grow);
            float pr[4][4], alpha[4];
            #pragma unroll
            for (int j = 0; j < 4; j++) {
                float mnew = skip ? m_run[j] : fmaxf(m_run[j], tmr[j]);
                float p0 = __expf(vv[0][j] - mnew), p1 = __expf(vv[1][j] - mnew);
                float p2 = __expf(vv[2][j] - mnew), p3 = __expf(vv[3][j] - mnew);
                float sum4 = (p0 + p1) + (p2 + p3);
                if (skip) {
                    l_part[j] += sum4;
                } else {
                    alpha[j] = __expf(m_run[j] - mnew);
                    l_part[j] = l_part[j] * alpha[j] + sum4;
                    m_run[j] = mnew;
                }
                pr[0][j] = p0; pr[1][j] = p1; pr[2][j] = p2; pr[3][j] = p3;
            }
            if (!skip) {
                #pragma unroll
                for (int f = 0; f < 4; f++)
                    #pragma unroll
                    for (int j = 0; j < 4; j++) O[f][j] *= alpha[j];
            }
            us* Pw = &P_lds[w][0];
            #pragma unroll
            for (int c = 0; c < 4; c++)
                #pragma unroll
                for (int j = 0; j < 4; j++)
                    Pw[(g4 * 4 + j) * 72 + c * 16 + l15] = f2bf(pr[c][j]);
            __builtin_amdgcn_s_setprio(1);
            #pragma unroll
            for (int kc = 0; kc < 2; kc++) {
                bf16x8 pa = *(const bf16x8*)&Pw[l15 * 72 + kc * 32 + g4 * 8];
                #pragma unroll
                for (int dt = 0; dt < 4; dt++) {
                    int row = dt * 16 + l15;
                    int ch = (kc * 4 + g4) ^ (row & 7);
                    bf16x8 vb = *(const bf16x8*)&VT_lds[bb][row * 64 + ch * 8];
                    O[dt] = __builtin_amdgcn_mfma_f32_16x16x32_bf16(pa, vb, O[dt], 0, 0, 0);
                }
            }
            __builtin_amdgcn_s_setprio(0);
        }
        __syncthreads();
    }
    float l_run[4];
    #pragma unroll
    for (int j = 0; j < 4; j++) {
        float l = l_part[j];
        l += __shfl_xor(l, 1, 16);
        l += __shfl_xor(l, 2, 16);
        l += __shfl_xor(l, 4, 16);
        l += __shfl_xor(l, 8, 16);
        l_run[j] = l;
    }
    #pragma unroll
    for (int dt = 0; dt < 4; dt++)
        #pragma unroll
        for (int j = 0; j < 4; j++) {
            size_t o = ((size_t)b * S + qrow_base + g4 * 4 + j) * E + h * 64 + dt * 16 + l15;
            x[o] += O[dt][j] / l_run[j];
        }
}

// ---------------------------------------------------------------- launch
extern "C" void kernel_launch(void* const* d_in, const int* in_sizes, int n_in,
                              void* d_out, int out_size, void* d_ws, size_t ws_size,
                              hipStream_t stream) {
    const int*   idx    = (const int*)d_in[0];
    const float* tok    = (const float*)d_in[1];
    const float* pos    = (const float*)d_in[2];
    const float* qkv_w  = (const float*)d_in[3];
    const float* qkv_b  = (const float*)d_in[4];
    const float* ln1_w  = (const float*)d_in[5];
    const float* ln1_b  = (const float*)d_in[6];
    const float* ln2_w  = (const float*)d_in[7];
    const float* ln2_b  = (const float*)d_in[8];
    const float* ff1_w  = (const float*)d_in[9];
    const float* ff1_b  = (const float*)d_in[10];
    const float* ff2_w  = (const float*)d_in[11];
    const float* ff2_b  = (const float*)d_in[12];
    const float* fin_w  = (const float*)d_in[13];
    const float* fin_b  = (const float*)d_in[14];
    const float* proj_w = (const float*)d_in[15];

    char* ws = (char*)d_ws;
    float* x    = (float*)ws;                          // 16.78 MB f32 residual
    us*    xn   = (us*)(ws + 16777216);                // 8.39 MB bf16 LN out
    us*    qkvb = (us*)(ws + 25165824);                // 25.17 MB bf16 qkv (Q,K) / ff1-w rider (V-third) / ff2 partials 0-2
    us*    hbuf = (us*)(ws + 50331648);                // 33.55 MB bf16 ff hidden
    us*    wbuf = (us*)(ws + 83886080);                // 8.39 MB bf16 qkv / ff2 weights
    us*    vTb  = (us*)(ws + 92274688);                // 8.39 MB bf16 V^T / ff2 partial 3
    us*    pbuf = qkvb;                                // 65.5 MB proj weights (qkvb..wbuf span, free then)

    embed_ln<<<NTOK, 256, 0, stream>>>(idx, tok, pos, ln1_w, ln1_b, x, xn);
    for (int l = 0; l < DEPTH; l++) {
        cast_kernel<<<1536, 256, 0, stream>>>(qkv_w + (size_t)l * 3 * E * E, wbuf, 3 * E * E / 8);
        // qkv (192 GEMM blocks) + 64 rider blocks casting ff1_w into qkvb's dead V-third (ld 3072)
        gemm256<1, 0, 1, 0, 1, 1><<<256, 512, 0, stream>>>(
            xn, E, wbuf, E, qkv_b + l * 3 * E, qkvb, nullptr, vTb,
            ff1_w + (size_t)l * 4 * E * E, qkvb + 2048, 3072, 192, NTOK, 3 * E, E, 3 * E);
        attn_kernel<<<dim3(S / 128, H, BB), 512, 0, stream>>>(qkvb, vTb, x);
        ln_kernel<<<NTOK, 256, 0, stream>>>(x, ln2_w + l * E, ln2_b + l * E, xn);
        // ff1 (256 GEMM blocks, B = ff1 weights in V-third, ldb 3072) + 64 riders casting ff2_w -> wbuf (flat)
        gemm256<1, 1, 1, 0, 0, 1><<<320, 512, 0, stream>>>(
            xn, E, qkvb + 2048, 3072, ff1_b + l * 4 * E, hbuf, nullptr, nullptr,
            ff2_w + (size_t)l * E * 4 * E, wbuf, 1024, 256, NTOK, 4 * E, E, 4 * E);
        // ff2: 256^2 8-phase split-K x4 (grid 256 = 1 block/CU), bf16 partials
        gemm256<1, 0, 0, 1, 0, 0><<<256, 512, 0, stream>>>(
            hbuf, 4 * E, wbuf, 4 * E, nullptr, qkvb, vTb, nullptr,
            nullptr, nullptr, 0, 256, NTOK, E, E, E);
        const float* nw = (l < DEPTH - 1) ? (ln1_w + (l + 1) * E) : fin_w;
        const float* nb = (l < DEPTH - 1) ? (ln1_b + (l + 1) * E) : fin_b;
        combine_ln<<<NTOK, 256, 0, stream>>>(qkvb, vTb, ff2_b + l * E, x, nw, nb, xn);
    }
    cast_kernel<<<16000, 256, 0, stream>>>(proj_w, pbuf, V * E / 8);
    gemm256<0, 0, 0, 0, 0, 0><<<2000, 512, 0, stream>>>(
        xn, E, pbuf, E, nullptr, d_out, nullptr, nullptr,
        nullptr, nullptr, 0, 2000, NTOK, V, E, V);
}

// Round 15
// 1675.816 us; speedup vs baseline: 1.0248x; 1.0117x over previous
//
#include <hip/hip_runtime.h>
#include <hip/hip_bf16.h>

#define DEPTH 6
#define E 1024
#define H 16
#define S 2048
#define V 32000
#define BB 2
#define HD 64
#define NTOK (BB * S)  // 4096

typedef __attribute__((ext_vector_type(8))) short bf16x8;
typedef __attribute__((ext_vector_type(4))) float f32x4;
typedef __attribute__((ext_vector_type(4))) unsigned int u32x4;
typedef unsigned short us;

__device__ inline us f2bf(float f) {
    union { float f; unsigned u; } v; v.f = f;
    unsigned r = v.u + 0x7fff + ((v.u >> 16) & 1);
    return (us)(r >> 16);
}
__device__ inline float bf2f(us b) {
    union { unsigned u; float f; } v; v.u = ((unsigned)b) << 16;
    return v.f;
}

__device__ __forceinline__ void gld16(const us* g, us* l) {
    __builtin_amdgcn_global_load_lds(
        (const __attribute__((address_space(1))) unsigned int*)g,
        (__attribute__((address_space(3))) unsigned int*)l, 16, 0, 0);
}

// ---------------------------------------------------------------- f32 -> bf16 cast (nt-loads: weights read once)
__global__ __launch_bounds__(256) void cast_kernel(const float* __restrict__ in,
                                                   us* __restrict__ out, int n8) {
    int i = blockIdx.x * 256 + threadIdx.x;
    if (i >= n8) return;
    f32x4 a = __builtin_nontemporal_load((const f32x4*)in + 2 * (size_t)i);
    f32x4 b = __builtin_nontemporal_load((const f32x4*)in + 2 * (size_t)i + 1);
    uint4 o;
    o.x = f2bf(a[0]) | ((unsigned)f2bf(a[1]) << 16);
    o.y = f2bf(a[2]) | ((unsigned)f2bf(a[3]) << 16);
    o.z = f2bf(b[0]) | ((unsigned)f2bf(b[1]) << 16);
    o.w = f2bf(b[2]) | ((unsigned)f2bf(b[3]) << 16);
    ((uint4*)out)[i] = o;
}

// ---------------------------------------------------------------- fused embedding + first layernorm
__global__ __launch_bounds__(256) void embed_ln(const int* __restrict__ idx,
                                                const float* __restrict__ tok,
                                                const float* __restrict__ pos,
                                                const float* __restrict__ w,
                                                const float* __restrict__ b,
                                                float* __restrict__ x,
                                                us* __restrict__ out) {
    int t = blockIdx.x;
    int s = t & (S - 1);
    int tokid = idx[t];
    int tid = threadIdx.x;
    int c = tid * 4;
    float4 a = *(const float4*)&tok[(size_t)tokid * E + c];
    float4 p = *(const float4*)&pos[(size_t)s * E + c];
    float4 v; v.x = a.x + p.x; v.y = a.y + p.y; v.z = a.z + p.z; v.w = a.w + p.w;
    *(float4*)&x[(size_t)t * E + c] = v;

    float sum = v.x + v.y + v.z + v.w;
    float sq  = v.x * v.x + v.y * v.y + v.z * v.z + v.w * v.w;
    __shared__ float red[8];
    for (int o = 32; o > 0; o >>= 1) { sum += __shfl_xor(sum, o); sq += __shfl_xor(sq, o); }
    int wave = tid >> 6, lane = tid & 63;
    if (lane == 0) { red[wave] = sum; red[4 + wave] = sq; }
    __syncthreads();
    if (tid == 0) {
        red[0] = red[0] + red[1] + red[2] + red[3];
        red[4] = red[4] + red[5] + red[6] + red[7];
    }
    __syncthreads();
    float mean = red[0] * (1.0f / E);
    float var  = red[4] * (1.0f / E) - mean * mean;
    float rstd = rsqrtf(var + 1e-5f);
    float4 wv = *(const float4*)&w[c];
    float4 bv = *(const float4*)&b[c];
    unsigned a0 = f2bf((v.x - mean) * rstd * wv.x + bv.x);
    unsigned a1 = f2bf((v.y - mean) * rstd * wv.y + bv.y);
    unsigned a2 = f2bf((v.z - mean) * rstd * wv.z + bv.z);
    unsigned a3 = f2bf((v.w - mean) * rstd * wv.w + bv.w);
    uint2 o; o.x = a0 | (a1 << 16); o.y = a2 | (a3 << 16);
    *(uint2*)&out[(size_t)t * E + c] = o;
}

// ---------------------------------------------------------------- layernorm
__global__ __launch_bounds__(256) void ln_kernel(const float* __restrict__ x,
                                                 const float* __restrict__ w,
                                                 const float* __restrict__ b,
                                                 us* __restrict__ out) {
    int row = blockIdx.x;
    int tid = threadIdx.x;
    int c = tid * 4;
    float4 v = *(const float4*)&x[(size_t)row * E + c];
    float s  = v.x + v.y + v.z + v.w;
    float sq = v.x * v.x + v.y * v.y + v.z * v.z + v.w * v.w;
    __shared__ float red[8];
    for (int o = 32; o > 0; o >>= 1) { s += __shfl_xor(s, o); sq += __shfl_xor(sq, o); }
    int wave = tid >> 6, lane = tid & 63;
    if (lane == 0) { red[wave] = s; red[4 + wave] = sq; }
    __syncthreads();
    if (tid == 0) {
        red[0] = red[0] + red[1] + red[2] + red[3];
        red[4] = red[4] + red[5] + red[6] + red[7];
    }
    __syncthreads();
    float mean = red[0] * (1.0f / E);
    float var  = red[4] * (1.0f / E) - mean * mean;
    float rstd = rsqrtf(var + 1e-5f);
    float4 wv = *(const float4*)&w[c];
    float4 bv = *(const float4*)&b[c];
    unsigned a0 = f2bf((v.x - mean) * rstd * wv.x + bv.x);
    unsigned a1 = f2bf((v.y - mean) * rstd * wv.y + bv.y);
    unsigned a2 = f2bf((v.z - mean) * rstd * wv.z + bv.z);
    unsigned a3 = f2bf((v.w - mean) * rstd * wv.w + bv.w);
    uint2 o; o.x = a0 | (a1 << 16); o.y = a2 | (a3 << 16);
    *(uint2*)&out[(size_t)row * E + c] = o;
}

// ---------------------------------------------------------------- fused ff2-combine (4 partials) + layernorm
__global__ __launch_bounds__(256) void combine_ln(const us* __restrict__ p012,
                                                  const us* __restrict__ p3,
                                                  const float* __restrict__ bias,
                                                  float* __restrict__ x,
                                                  const float* __restrict__ w,
                                                  const float* __restrict__ b,
                                                  us* __restrict__ out) {
    int row = blockIdx.x;
    int tid = threadIdx.x;
    int c = tid * 4;
    size_t base = (size_t)row * E + c;
    const size_t stride = (size_t)NTOK * E;
    float4 v = *(const float4*)&x[base];
    uint2 a0 = *(const uint2*)&p012[base];
    uint2 a1 = *(const uint2*)&p012[base + stride];
    uint2 a2 = *(const uint2*)&p012[base + 2 * stride];
    uint2 a3 = *(const uint2*)&p3[base];
    float4 bi = *(const float4*)&bias[c];
    v.x += bf2f((us)(a0.x & 0xffff)) + bf2f((us)(a1.x & 0xffff)) + bf2f((us)(a2.x & 0xffff)) + bf2f((us)(a3.x & 0xffff)) + bi.x;
    v.y += bf2f((us)(a0.x >> 16))    + bf2f((us)(a1.x >> 16))    + bf2f((us)(a2.x >> 16))    + bf2f((us)(a3.x >> 16))    + bi.y;
    v.z += bf2f((us)(a0.y & 0xffff)) + bf2f((us)(a1.y & 0xffff)) + bf2f((us)(a2.y & 0xffff)) + bf2f((us)(a3.y & 0xffff)) + bi.z;
    v.w += bf2f((us)(a0.y >> 16))    + bf2f((us)(a1.y >> 16))    + bf2f((us)(a2.y >> 16))    + bf2f((us)(a3.y >> 16))    + bi.w;
    *(float4*)&x[base] = v;

    float s  = v.x + v.y + v.z + v.w;
    float sq = v.x * v.x + v.y * v.y + v.z * v.z + v.w * v.w;
    __shared__ float red[8];
    for (int o = 32; o > 0; o >>= 1) { s += __shfl_xor(s, o); sq += __shfl_xor(sq, o); }
    int wave = tid >> 6, lane = tid & 63;
    if (lane == 0) { red[wave] = s; red[4 + wave] = sq; }
    __syncthreads();
    if (tid == 0) {
        red[0] = red[0] + red[1] + red[2] + red[3];
        red[4] = red[4] + red[5] + red[6] + red[7];
    }
    __syncthreads();
    float mean = red[0] * (1.0f / E);
    float var  = red[4] * (1.0f / E) - mean * mean;
    float rstd = rsqrtf(var + 1e-5f);
    float4 wv = *(const float4*)&w[c];
    float4 bv = *(const float4*)&b[c];
    unsigned b0 = f2bf((v.x - mean) * rstd * wv.x + bv.x);
    unsigned b1 = f2bf((v.y - mean) * rstd * wv.y + bv.y);
    unsigned b2 = f2bf((v.z - mean) * rstd * wv.z + bv.z);
    unsigned b3 = f2bf((v.w - mean) * rstd * wv.w + bv.w);
    uint2 o; o.x = b0 | (b1 << 16); o.y = b2 | (b3 << 16);
    *(uint2*)&out[base] = o;
}

// ================================================================ 256x256 8-phase GEMM (T2+T3+T4+T5)
// ISVM: 0 = none, 1 = vmcnt(6), 2 = vmcnt(0) (peeled-tail drain)
#define GPH(dd, fb, STAGE, ISVM, IS12)                                              \
  {                                                                                 \
    bf16x8 afr0[2], afr1[2];                                                        \
    if ((fb) == 0) {                                                                \
      _Pragma("unroll")                                                             \
      for (int n = 0; n < 4; n++)                                                   \
        _Pragma("unroll")                                                           \
        for (int ks = 0; ks < 2; ks++)                                              \
          bfr[n][ks] = *(const bf16x8*)&lds[32768 + (dd) * 16384 +                  \
              (brow + n * 16) * 64 + ((ks * 4 + g4) ^ xg) * 8];                     \
    }                                                                               \
    _Pragma("unroll")                                                               \
    for (int ks = 0; ks < 2; ks++) {                                                \
      afr0[ks] = *(const bf16x8*)&lds[(dd) * 16384 + ((fb) >> 1) * 4096 +           \
          arow0 * 64 + ((ks * 4 + g4) ^ xg) * 8];                                   \
      afr1[ks] = *(const bf16x8*)&lds[(dd) * 16384 + ((fb) >> 1) * 4096 +           \
          arow1 * 64 + ((ks * 4 + g4) ^ xg) * 8];                                   \
    }                                                                               \
    STAGE;                                                                          \
    __builtin_amdgcn_sched_barrier(0);                                              \
    if (IS12) asm volatile("s_waitcnt lgkmcnt(8)" ::: "memory");                    \
    __builtin_amdgcn_s_barrier();                                                   \
    asm volatile("s_waitcnt lgkmcnt(0)" ::: "memory");                              \
    __builtin_amdgcn_sched_barrier(0);                                              \
    __builtin_amdgcn_s_setprio(1);                                                  \
    _Pragma("unroll")                                                               \
    for (int n = 0; n < 4; n++)                                                     \
      _Pragma("unroll")                                                             \
      for (int ks = 0; ks < 2; ks++) {                                              \
        acc[(fb)][n]     = __builtin_amdgcn_mfma_f32_16x16x32_bf16(afr0[ks], bfr[n][ks], acc[(fb)][n], 0, 0, 0);     \
        acc[(fb) + 1][n] = __builtin_amdgcn_mfma_f32_16x16x32_bf16(afr1[ks], bfr[n][ks], acc[(fb) + 1][n], 0, 0, 0); \
      }                                                                             \
    __builtin_amdgcn_s_setprio(0);                                                  \
    __builtin_amdgcn_sched_barrier(0);                                              \
    if ((ISVM) == 1) asm volatile("s_waitcnt vmcnt(6)" ::: "memory");               \
    if ((ISVM) == 2) asm volatile("s_waitcnt vmcnt(0)" ::: "memory");               \
    __builtin_amdgcn_s_barrier();                                                   \
  }

// SPLITK=0: sw -> (bm,bn) M-fastest over gemm_nwg blocks. SPLITK=1: kz chunks of K.
// WRITE_VT: qkv mode — V-tiles (bn>=2048) write transposed to vt[b][h][d][s].
// RIDER: blocks with wgid >= gemm_nwg grid-stride cast csrc(f32) -> cdst(bf16).
// Epilogue: LDS-transpose — scatter C into LDS, read back linear, 16B/lane stores.
template <int OUT_BF16, int ACT_GELU, int HAS_BIAS, int SPLITK, int WRITE_VT, int RIDER>
__global__ __launch_bounds__(512, 2) void gemm256(const us* __restrict__ A, int lda,
                                                  const us* __restrict__ Bw, int ldb,
                                                  const float* __restrict__ bias,
                                                  void* __restrict__ outp,
                                                  void* __restrict__ outp3,
                                                  us* __restrict__ vt,
                                                  const float* __restrict__ csrc,
                                                  us* __restrict__ cdst,
                                                  int dst_ld, int gemm_nwg,
                                                  int M, int N, int K, int ldo) {
    int tid = threadIdx.x;
    int wgid = blockIdx.x;
    if (RIDER && wgid >= gemm_nwg) {
        int nrb = gridDim.x - gemm_nwg;
        int rtid = (wgid - gemm_nwg) * 512 + tid;
        int nthr = nrb * 512;
        for (int j = rtid; j < 4 * E * E / 8; j += nthr) {
            f32x4 a = __builtin_nontemporal_load((const f32x4*)csrc + 2 * (size_t)j);
            f32x4 b = __builtin_nontemporal_load((const f32x4*)csrc + 2 * (size_t)j + 1);
            uint4 o;
            o.x = f2bf(a[0]) | ((unsigned)f2bf(a[1]) << 16);
            o.y = f2bf(a[2]) | ((unsigned)f2bf(a[3]) << 16);
            o.z = f2bf(b[0]) | ((unsigned)f2bf(b[1]) << 16);
            o.w = f2bf(b[2]) | ((unsigned)f2bf(b[3]) << 16);
            int n = j >> 7, c8 = (j & 127) << 3;
            *(uint4*)&cdst[(size_t)n * dst_ld + c8] = o;
        }
        return;
    }
    __shared__ us lds[65536];
    int chunk = gemm_nwg >> 3;
    int sw = (wgid & 7) * chunk + (wgid >> 3);
    int MB = M >> 8;
    int bm, bn;
    us* outb;
    float* outf = (float*)outp;
    if (SPLITK) {
        int ntile = MB * (N >> 8);
        int kz = sw / ntile;
        int rem = sw % ntile;
        bm = (rem % MB) * 256;
        bn = (rem / MB) * 256;
        A  += (size_t)kz * K;
        Bw += (size_t)kz * K;
        outb = (kz < 3) ? (us*)outp + (size_t)kz * M * ldo : (us*)outp3;
    } else {
        bm = (sw % MB) * 256;
        bn = (sw / MB) * 256;
        outb = (us*)outp;
    }
    int w = tid >> 6, lane = tid & 63;
    int wr = w >> 2, wc = w & 3;
    int l15 = lane & 15, g4 = lane >> 4;
    int xg = l15 & 7;
    int arow0 = (wr ? 32 : 0) + l15;
    int arow1 = arow0 + 16;
    int brow = wc * 64 + l15;
    int NT = K >> 6;

    f32x4 acc[8][4] = {};
    bf16x8 bfr[4][2];

    auto stA = [&](int u, int dd, int h) {
        #pragma unroll
        for (int i = 0; i < 2; i++) {
            int k = tid + i * 512;
            int q = 2 * h + (k >> 9);
            int r = (k >> 3) & 63;
            int tr = q * 32 + (r & 31) + ((r >> 5) << 7);
            int gp = (k & 7) ^ (r & 7);
            gld16(A + (size_t)(bm + tr) * lda + u * 64 + gp * 8,
                  &lds[dd * 16384 + h * 8192 + k * 8]);
        }
    };
    auto stB = [&](int u, int dd, int h) {
        #pragma unroll
        for (int i = 0; i < 2; i++) {
            int k = tid + i * 512;
            int row = h * 128 + (k >> 3);
            int gp = (k & 7) ^ ((k >> 3) & 7);
            gld16(Bw + (size_t)(bn + row) * ldb + u * 64 + gp * 8,
                  &lds[32768 + dd * 16384 + h * 8192 + k * 8]);
        }
    };

    stB(0, 0, 0); stB(0, 0, 1); stA(0, 0, 0); stA(0, 0, 1);
    stB(1, 1, 0); stB(1, 1, 1); stA(1, 1, 0);
    __builtin_amdgcn_sched_barrier(0);
    asm volatile("s_waitcnt vmcnt(6)" ::: "memory");
    __builtin_amdgcn_s_barrier();

    #pragma unroll 1
    for (int t = 0; t < NT - 2; t += 2) {
        GPH(0, 0, stA(t + 1, 1, 1), 0, 1)
        GPH(0, 2, stB(t + 2, 0, 0), 0, 0)
        GPH(0, 4, stB(t + 2, 0, 1), 0, 0)
        GPH(0, 6, stA(t + 2, 0, 0), 1, 0)
        GPH(1, 0, stA(t + 2, 0, 1), 0, 1)
        GPH(1, 2, stB(t + 3, 1, 0), 0, 0)
        GPH(1, 4, stB(t + 3, 1, 1), 0, 0)
        GPH(1, 6, stA(t + 3, 1, 0), 1, 0)
    }
    // peeled final iteration (tiles NT-2, NT-1): no beyond-range prefetch.
    GPH(0, 0, stA(NT - 1, 1, 1), 0, 1)
    GPH(0, 2, , 0, 0)
    GPH(0, 4, , 0, 0)
    GPH(0, 6, , 2, 0)
    GPH(1, 0, , 0, 1)
    GPH(1, 2, , 0, 0)
    GPH(1, 4, , 0, 0)
    GPH(1, 6, , 0, 0)
    // (last GPH ends with s_barrier: all LDS reads complete -> lds reusable)

    if (WRITE_VT && bn >= 2048) {
        // V tile: write transposed, packed 4 consecutive s per lane (8B store)
        #pragma unroll
        for (int mf = 0; mf < 8; mf++)
            #pragma unroll
            for (int n = 0; n < 4; n++) {
                int r = bm + wr * 128 + mf * 16 + g4 * 4;
                int c = bn + wc * 64 + n * 16 + l15;
                int hh = (c - 2048) >> 6, d = (c - 2048) & 63;
                int bq = r >> 11, s = r & (S - 1);
                float bv = HAS_BIAS ? bias[c] : 0.0f;
                unsigned o0 = f2bf(acc[mf][n][0] + bv) | ((unsigned)f2bf(acc[mf][n][1] + bv) << 16);
                unsigned o1 = f2bf(acc[mf][n][2] + bv) | ((unsigned)f2bf(acc[mf][n][3] + bv) << 16);
                uint2 pk; pk.x = o0; pk.y = o1;
                *(uint2*)&vt[(((size_t)(bq * H + hh) * 64 + d) << 11) + s] = pk;
            }
        return;
    }

    if (OUT_BF16) {
        // scatter C (bf16) into LDS [256][256], then linear read-back, 16B/lane stores
        #pragma unroll
        for (int mf = 0; mf < 8; mf++)
            #pragma unroll
            for (int n = 0; n < 4; n++)
                #pragma unroll
                for (int j = 0; j < 4; j++) {
                    int r = wr * 128 + mf * 16 + g4 * 4 + j;
                    int c = wc * 64 + n * 16 + l15;
                    float v = acc[mf][n][j];
                    if (HAS_BIAS) v += bias[bn + c];
                    if (ACT_GELU) v = 0.5f * v * (1.0f + erff(v * 0.70710678118f));
                    lds[r * 256 + c] = f2bf(v);
                }
        __builtin_amdgcn_s_barrier();
        #pragma unroll
        for (int it = 0; it < 16; it++) {
            int idx = it * 512 + tid;
            int row = idx >> 5, c16 = idx & 31;
            u32x4 v = *(const u32x4*)&lds[row * 256 + c16 * 8];
            *(u32x4*)&outb[(size_t)(bm + row) * ldo + bn + c16 * 8] = v;
        }
    } else {
        // f32: two 128-col halves through LDS [256][128] f32
        float* lf = (float*)lds;
        #pragma unroll
        for (int half = 0; half < 2; half++) {
            if ((wc >> 1) == half) {
                #pragma unroll
                for (int mf = 0; mf < 8; mf++)
                    #pragma unroll
                    for (int n = 0; n < 4; n++)
                        #pragma unroll
                        for (int j = 0; j < 4; j++) {
                            int r = wr * 128 + mf * 16 + g4 * 4 + j;
                            int c = (wc & 1) * 64 + n * 16 + l15;
                            float v = acc[mf][n][j];
                            if (HAS_BIAS) v += bias[bn + half * 128 + c];
                            lf[r * 128 + c] = v;
                        }
            }
            __builtin_amdgcn_s_barrier();
            #pragma unroll
            for (int it = 0; it < 16; it++) {
                int idx = it * 512 + tid;
                int row = idx >> 5, c16 = idx & 31;
                f32x4 v = *(const f32x4*)&lf[row * 128 + c16 * 4];
                __builtin_nontemporal_store(v,
                    (f32x4*)&outf[(size_t)(bm + row) * ldo + bn + half * 128 + c16 * 4]);
            }
            if (half == 0) __builtin_amdgcn_s_barrier();
        }
    }
}

// ---------------------------------------------------------------- flash attention: 8 waves, QBLK=128, KVB=64
// causal load-balance: b==1 blocks take reversed qt so each CU pairs heavy+light
__global__ __launch_bounds__(512, 4) void attn_kernel(const us* __restrict__ qkv,
                                                      const us* __restrict__ vT,
                                                      float* __restrict__ x) {
    int qt = blockIdx.x, h = blockIdx.y, b = blockIdx.z;
    if (b == 1) qt = (S / 128 - 1) - qt;   // heavy+light pairing per CU
    int tid = threadIdx.x;
    int w = tid >> 6, lane = tid & 63;
    int l15 = lane & 15, g4 = lane >> 4;
    int s0 = qt * 128;
    int qrow_base = s0 + w * 16;
    const size_t qbase = (size_t)b * S * 3072;
    const size_t vtbase = ((size_t)(b * H + h) * 64) * S;

    __shared__ us K_lds[2][64 * 64];
    __shared__ us VT_lds[2][64 * 64];
    __shared__ us P_lds[8][16 * 72];

    bf16x8 q[2];
    #pragma unroll
    for (int dc = 0; dc < 2; dc++) {
        q[dc] = *(const bf16x8*)&qkv[qbase + (size_t)(qrow_base + l15) * 3072 + h * 64 + dc * 32 + 8 * g4];
        us* qq = (us*)&q[dc];
        #pragma unroll
        for (int e = 0; e < 8; e++) qq[e] = f2bf(bf2f(qq[e]) * 0.125f);  // fold 1/sqrt(d)
    }

    f32x4 O[4] = {};
    float m_run[4], l_part[4];
    #pragma unroll
    for (int j = 0; j < 4; j++) { m_run[j] = -INFINITY; l_part[j] = 0.0f; }

    int lastt = 2 * qt + 1;
    {
        int p = tid, row = p >> 3, cc = p & 7;
        int scc = cc ^ (row & 7);
        gld16(&qkv[qbase + (size_t)(0 + row) * 3072 + 1024 + h * 64 + scc * 8], &K_lds[0][p * 8]);
        gld16(&vT[vtbase + (size_t)row * S + 0 + scc * 8], &VT_lds[0][p * 8]);
    }
    __syncthreads();

    for (int t = 0; t <= lastt; t++) {
        int bb = t & 1;
        if (t < lastt) {
            int p = tid, row = p >> 3, cc = p & 7;
            int scc = cc ^ (row & 7);
            gld16(&qkv[qbase + (size_t)((t + 1) * 64 + row) * 3072 + 1024 + h * 64 + scc * 8], &K_lds[bb ^ 1][p * 8]);
            gld16(&vT[vtbase + (size_t)row * S + (t + 1) * 64 + scc * 8], &VT_lds[bb ^ 1][p * 8]);
        }
        int k0 = t * 64;
        if (k0 <= qrow_base + 15) {
            f32x4 sf[4];
            __builtin_amdgcn_s_setprio(1);
            #pragma unroll
            for (int c = 0; c < 4; c++) {
                f32x4 z = {};
                int row = c * 16 + l15;
                #pragma unroll
                for (int dc = 0; dc < 2; dc++) {
                    int ch = (dc * 4 + g4) ^ (row & 7);
                    bf16x8 kb = *(const bf16x8*)&K_lds[bb][row * 64 + ch * 8];
                    z = __builtin_amdgcn_mfma_f32_16x16x32_bf16(q[dc], kb, z, 0, 0, 0);
                }
                sf[c] = z;
            }
            __builtin_amdgcn_s_setprio(0);
            bool needmask = (k0 + 63 > qrow_base);
            float vv[4][4], tmr[4];
            #pragma unroll
            for (int j = 0; j < 4; j++) {
                int qrow = qrow_base + g4 * 4 + j;
                float v0 = sf[0][j], v1 = sf[1][j];
                float v2 = sf[2][j], v3 = sf[3][j];
                if (needmask) {
                    if (k0 +      l15 > qrow) v0 = -INFINITY;
                    if (k0 + 16 + l15 > qrow) v1 = -INFINITY;
                    if (k0 + 32 + l15 > qrow) v2 = -INFINITY;
                    if (k0 + 48 + l15 > qrow) v3 = -INFINITY;
                }
                float tm = fmaxf(fmaxf(v0, v1), fmaxf(v2, v3));
                tm = fmaxf(tm, __shfl_xor(tm, 1, 16));
                tm = fmaxf(tm, __shfl_xor(tm, 2, 16));
                tm = fmaxf(tm, __shfl_xor(tm, 4, 16));
                tm = fmaxf(tm, __shfl_xor(tm, 8, 16));
                tmr[j] = tm;
                vv[0][j] = v0; vv[1][j] = v1; vv[2][j] = v2; vv[3][j] = v3;
            }
            bool grow = (tmr[0] > m_run[0] + 8.0f) || (tmr[1] > m_run[1] + 8.0f) ||
                        (tmr[2] > m_run[2] + 8.0f) || (tmr[3] > m_run[3] + 8.0f);
            bool skip = !__any(grow);
            float pr[4][4], alpha[4];
            #pragma unroll
            for (int j = 0; j < 4; j++) {
                float mnew = skip ? m_run[j] : fmaxf(m_run[j], tmr[j]);
                float p0 = __expf(vv[0][j] - mnew), p1 = __expf(vv[1][j] - mnew);
                float p2 = __expf(vv[2][j] - mnew), p3 = __expf(vv[3][j] - mnew);
                float sum4 = (p0 + p1) + (p2 + p3);
                if (skip) {
                    l_part[j] += sum4;
                } else {
                    alpha[j] = __expf(m_run[j] - mnew);
                    l_part[j] = l_part[j] * alpha[j] + sum4;
                    m_run[j] = mnew;
                }
                pr[0][j] = p0; pr[1][j] = p1; pr[2][j] = p2; pr[3][j] = p3;
            }
            if (!skip) {
                #pragma unroll
                for (int f = 0; f < 4; f++)
                    #pragma unroll
                    for (int j = 0; j < 4; j++) O[f][j] *= alpha[j];
            }
            us* Pw = &P_lds[w][0];
            #pragma unroll
            for (int c = 0; c < 4; c++)
                #pragma unroll
                for (int j = 0; j < 4; j++)
                    Pw[(g4 * 4 + j) * 72 + c * 16 + l15] = f2bf(pr[c][j]);
            __builtin_amdgcn_s_setprio(1);
            #pragma unroll
            for (int kc = 0; kc < 2; kc++) {
                bf16x8 pa = *(const bf16x8*)&Pw[l15 * 72 + kc * 32 + g4 * 8];
                #pragma unroll
                for (int dt = 0; dt < 4; dt++) {
                    int row = dt * 16 + l15;
                    int ch = (kc * 4 + g4) ^ (row & 7);
                    bf16x8 vb = *(const bf16x8*)&VT_lds[bb][row * 64 + ch * 8];
                    O[dt] = __builtin_amdgcn_mfma_f32_16x16x32_bf16(pa, vb, O[dt], 0, 0, 0);
                }
            }
            __builtin_amdgcn_s_setprio(0);
        }
        __syncthreads();
    }
    float l_run[4];
    #pragma unroll
    for (int j = 0; j < 4; j++) {
        float l = l_part[j];
        l += __shfl_xor(l, 1, 16);
        l += __shfl_xor(l, 2, 16);
        l += __shfl_xor(l, 4, 16);
        l += __shfl_xor(l, 8, 16);
        l_run[j] = l;
    }
    #pragma unroll
    for (int dt = 0; dt < 4; dt++)
        #pragma unroll
        for (int j = 0; j < 4; j++) {
            size_t o = ((size_t)b * S + qrow_base + g4 * 4 + j) * E + h * 64 + dt * 16 + l15;
            x[o] += O[dt][j] / l_run[j];
        }
}

// ---------------------------------------------------------------- launch
extern "C" void kernel_launch(void* const* d_in, const int* in_sizes, int n_in,
                              void* d_out, int out_size, void* d_ws, size_t ws_size,
                              hipStream_t stream) {
    const int*   idx    = (const int*)d_in[0];
    const float* tok    = (const float*)d_in[1];
    const float* pos    = (const float*)d_in[2];
    const float* qkv_w  = (const float*)d_in[3];
    const float* qkv_b  = (const float*)d_in[4];
    const float* ln1_w  = (const float*)d_in[5];
    const float* ln1_b  = (const float*)d_in[6];
    const float* ln2_w  = (const float*)d_in[7];
    const float* ln2_b  = (const float*)d_in[8];
    const float* ff1_w  = (const float*)d_in[9];
    const float* ff1_b  = (const float*)d_in[10];
    const float* ff2_w  = (const float*)d_in[11];
    const float* ff2_b  = (const float*)d_in[12];
    const float* fin_w  = (const float*)d_in[13];
    const float* fin_b  = (const float*)d_in[14];
    const float* proj_w = (const float*)d_in[15];

    char* ws = (char*)d_ws;
    float* x    = (float*)ws;                          // 16.78 MB f32 residual
    us*    xn   = (us*)(ws + 16777216);                // 8.39 MB bf16 LN out
    us*    qkvb = (us*)(ws + 25165824);                // 25.17 MB bf16 qkv (Q,K) / ff1-w rider (V-third) / ff2 partials 0-2
    us*    hbuf = (us*)(ws + 50331648);                // 33.55 MB bf16 ff hidden
    us*    wbuf = (us*)(ws + 83886080);                // 8.39 MB bf16 qkv / ff2 weights
    us*    vTb  = (us*)(ws + 92274688);                // 8.39 MB bf16 V^T / ff2 partial 3
    us*    pbuf = qkvb;                                // 65.5 MB proj weights (qkvb..wbuf span, free then)

    embed_ln<<<NTOK, 256, 0, stream>>>(idx, tok, pos, ln1_w, ln1_b, x, xn);
    for (int l = 0; l < DEPTH; l++) {
        cast_kernel<<<1536, 256, 0, stream>>>(qkv_w + (size_t)l * 3 * E * E, wbuf, 3 * E * E / 8);
        // qkv (192 GEMM blocks) + 64 rider blocks casting ff1_w into qkvb's dead V-third (ld 3072)
        gemm256<1, 0, 1, 0, 1, 1><<<256, 512, 0, stream>>>(
            xn, E, wbuf, E, qkv_b + l * 3 * E, qkvb, nullptr, vTb,
            ff1_w + (size_t)l * 4 * E * E, qkvb + 2048, 3072, 192, NTOK, 3 * E, E, 3 * E);
        attn_kernel<<<dim3(S / 128, H, BB), 512, 0, stream>>>(qkvb, vTb, x);
        ln_kernel<<<NTOK, 256, 0, stream>>>(x, ln2_w + l * E, ln2_b + l * E, xn);
        // ff1 (256 GEMM blocks, B = ff1 weights in V-third, ldb 3072) + 64 riders casting ff2_w -> wbuf (flat)
        gemm256<1, 1, 1, 0, 0, 1><<<320, 512, 0, stream>>>(
            xn, E, qkvb + 2048, 3072, ff1_b + l * 4 * E, hbuf, nullptr, nullptr,
            ff2_w + (size_t)l * E * 4 * E, wbuf, 1024, 256, NTOK, 4 * E, E, 4 * E);
        // ff2: 256^2 8-phase split-K x4 (grid 256 = 1 block/CU), bf16 partials
        gemm256<1, 0, 0, 1, 0, 0><<<256, 512, 0, stream>>>(
            hbuf, 4 * E, wbuf, 4 * E, nullptr, qkvb, vTb, nullptr,
            nullptr, nullptr, 0, 256, NTOK, E, E, E);
        const float* nw = (l < DEPTH - 1) ? (ln1_w + (l + 1) * E) : fin_w;
        const float* nb = (l < DEPTH - 1) ? (ln1_b + (l + 1) * E) : fin_b;
        combine_ln<<<NTOK, 256, 0, stream>>>(qkvb, vTb, ff2_b + l * E, x, nw, nb, xn);
    }
    cast_kernel<<<16000, 256, 0, stream>>>(proj_w, pbuf, V * E / 8);
    gemm256<0, 0, 0, 0, 0, 0><<<2000, 512, 0, stream>>>(
        xn, E, pbuf, E, nullptr, d_out, nullptr, nullptr,
        nullptr, nullptr, 0, 2000, NTOK, V, E, V);
}

// Round 16
// 1666.307 us; speedup vs baseline: 1.0306x; 1.0057x over previous
//
#include <hip/hip_runtime.h>
#include <hip/hip_bf16.h>

#define DEPTH 6
#define E 1024
#define H 16
#define S 2048
#define V 32000
#define BB 2
#define HD 64
#define NTOK (BB * S)  // 4096

typedef __attribute__((ext_vector_type(8))) short bf16x8;
typedef __attribute__((ext_vector_type(4))) float f32x4;
typedef __attribute__((ext_vector_type(4))) unsigned int u32x4;
typedef unsigned short us;

__device__ inline us f2bf(float f) {
    union { float f; unsigned u; } v; v.f = f;
    unsigned r = v.u + 0x7fff + ((v.u >> 16) & 1);
    return (us)(r >> 16);
}
__device__ inline float bf2f(us b) {
    union { unsigned u; float f; } v; v.u = ((unsigned)b) << 16;
    return v.f;
}

// fast gelu: erf via Abramowitz-Stegun 7.1.26 (max err 1.5e-7)
__device__ inline float gelu(float v) {
    float y = fabsf(v) * 0.70710678118f;
    float t = __builtin_amdgcn_rcpf(fmaf(0.3275911f, y, 1.0f));
    float p = t * fmaf(t, fmaf(t, fmaf(t, fmaf(t, 1.061405429f, -1.453152027f),
                                       1.421413741f), -0.284496736f), 0.254829592f);
    float e = __expf(-y * y);
    float erfv = 1.0f - p * e;           // erf(|v|/sqrt2)
    float cdf = 0.5f * (1.0f + (v < 0.0f ? -erfv : erfv));
    return v * cdf;
}

__device__ __forceinline__ void gld16(const us* g, us* l) {
    __builtin_amdgcn_global_load_lds(
        (const __attribute__((address_space(1))) unsigned int*)g,
        (__attribute__((address_space(3))) unsigned int*)l, 16, 0, 0);
}

// ---------------------------------------------------------------- f32 -> bf16 cast (nt-loads: weights read once)
__global__ __launch_bounds__(256) void cast_kernel(const float* __restrict__ in,
                                                   us* __restrict__ out, int n8) {
    int i = blockIdx.x * 256 + threadIdx.x;
    if (i >= n8) return;
    f32x4 a = __builtin_nontemporal_load((const f32x4*)in + 2 * (size_t)i);
    f32x4 b = __builtin_nontemporal_load((const f32x4*)in + 2 * (size_t)i + 1);
    uint4 o;
    o.x = f2bf(a[0]) | ((unsigned)f2bf(a[1]) << 16);
    o.y = f2bf(a[2]) | ((unsigned)f2bf(a[3]) << 16);
    o.z = f2bf(b[0]) | ((unsigned)f2bf(b[1]) << 16);
    o.w = f2bf(b[2]) | ((unsigned)f2bf(b[3]) << 16);
    ((uint4*)out)[i] = o;
}

// ---------------------------------------------------------------- fused embedding + first layernorm
__global__ __launch_bounds__(256) void embed_ln(const int* __restrict__ idx,
                                                const float* __restrict__ tok,
                                                const float* __restrict__ pos,
                                                const float* __restrict__ w,
                                                const float* __restrict__ b,
                                                float* __restrict__ x,
                                                us* __restrict__ out) {
    int t = blockIdx.x;
    int s = t & (S - 1);
    int tokid = idx[t];
    int tid = threadIdx.x;
    int c = tid * 4;
    float4 a = *(const float4*)&tok[(size_t)tokid * E + c];
    float4 p = *(const float4*)&pos[(size_t)s * E + c];
    float4 v; v.x = a.x + p.x; v.y = a.y + p.y; v.z = a.z + p.z; v.w = a.w + p.w;
    *(float4*)&x[(size_t)t * E + c] = v;

    float sum = v.x + v.y + v.z + v.w;
    float sq  = v.x * v.x + v.y * v.y + v.z * v.z + v.w * v.w;
    __shared__ float red[8];
    for (int o = 32; o > 0; o >>= 1) { sum += __shfl_xor(sum, o); sq += __shfl_xor(sq, o); }
    int wave = tid >> 6, lane = tid & 63;
    if (lane == 0) { red[wave] = sum; red[4 + wave] = sq; }
    __syncthreads();
    if (tid == 0) {
        red[0] = red[0] + red[1] + red[2] + red[3];
        red[4] = red[4] + red[5] + red[6] + red[7];
    }
    __syncthreads();
    float mean = red[0] * (1.0f / E);
    float var  = red[4] * (1.0f / E) - mean * mean;
    float rstd = rsqrtf(var + 1e-5f);
    float4 wv = *(const float4*)&w[c];
    float4 bv = *(const float4*)&b[c];
    unsigned a0 = f2bf((v.x - mean) * rstd * wv.x + bv.x);
    unsigned a1 = f2bf((v.y - mean) * rstd * wv.y + bv.y);
    unsigned a2 = f2bf((v.z - mean) * rstd * wv.z + bv.z);
    unsigned a3 = f2bf((v.w - mean) * rstd * wv.w + bv.w);
    uint2 o; o.x = a0 | (a1 << 16); o.y = a2 | (a3 << 16);
    *(uint2*)&out[(size_t)t * E + c] = o;
}

// ---------------------------------------------------------------- layernorm
__global__ __launch_bounds__(256) void ln_kernel(const float* __restrict__ x,
                                                 const float* __restrict__ w,
                                                 const float* __restrict__ b,
                                                 us* __restrict__ out) {
    int row = blockIdx.x;
    int tid = threadIdx.x;
    int c = tid * 4;
    float4 v = *(const float4*)&x[(size_t)row * E + c];
    float s  = v.x + v.y + v.z + v.w;
    float sq = v.x * v.x + v.y * v.y + v.z * v.z + v.w * v.w;
    __shared__ float red[8];
    for (int o = 32; o > 0; o >>= 1) { s += __shfl_xor(s, o); sq += __shfl_xor(sq, o); }
    int wave = tid >> 6, lane = tid & 63;
    if (lane == 0) { red[wave] = s; red[4 + wave] = sq; }
    __syncthreads();
    if (tid == 0) {
        red[0] = red[0] + red[1] + red[2] + red[3];
        red[4] = red[4] + red[5] + red[6] + red[7];
    }
    __syncthreads();
    float mean = red[0] * (1.0f / E);
    float var  = red[4] * (1.0f / E) - mean * mean;
    float rstd = rsqrtf(var + 1e-5f);
    float4 wv = *(const float4*)&w[c];
    float4 bv = *(const float4*)&b[c];
    unsigned a0 = f2bf((v.x - mean) * rstd * wv.x + bv.x);
    unsigned a1 = f2bf((v.y - mean) * rstd * wv.y + bv.y);
    unsigned a2 = f2bf((v.z - mean) * rstd * wv.z + bv.z);
    unsigned a3 = f2bf((v.w - mean) * rstd * wv.w + bv.w);
    uint2 o; o.x = a0 | (a1 << 16); o.y = a2 | (a3 << 16);
    *(uint2*)&out[(size_t)row * E + c] = o;
}

// ---------------------------------------------------------------- fused ff2-combine (4 partials) + layernorm
__global__ __launch_bounds__(256) void combine_ln(const us* __restrict__ p012,
                                                  const us* __restrict__ p3,
                                                  const float* __restrict__ bias,
                                                  float* __restrict__ x,
                                                  const float* __restrict__ w,
                                                  const float* __restrict__ b,
                                                  us* __restrict__ out) {
    int row = blockIdx.x;
    int tid = threadIdx.x;
    int c = tid * 4;
    size_t base = (size_t)row * E + c;
    const size_t stride = (size_t)NTOK * E;
    float4 v = *(const float4*)&x[base];
    uint2 a0 = *(const uint2*)&p012[base];
    uint2 a1 = *(const uint2*)&p012[base + stride];
    uint2 a2 = *(const uint2*)&p012[base + 2 * stride];
    uint2 a3 = *(const uint2*)&p3[base];
    float4 bi = *(const float4*)&bias[c];
    v.x += bf2f((us)(a0.x & 0xffff)) + bf2f((us)(a1.x & 0xffff)) + bf2f((us)(a2.x & 0xffff)) + bf2f((us)(a3.x & 0xffff)) + bi.x;
    v.y += bf2f((us)(a0.x >> 16))    + bf2f((us)(a1.x >> 16))    + bf2f((us)(a2.x >> 16))    + bf2f((us)(a3.x >> 16))    + bi.y;
    v.z += bf2f((us)(a0.y & 0xffff)) + bf2f((us)(a1.y & 0xffff)) + bf2f((us)(a2.y & 0xffff)) + bf2f((us)(a3.y & 0xffff)) + bi.z;
    v.w += bf2f((us)(a0.y >> 16))    + bf2f((us)(a1.y >> 16))    + bf2f((us)(a2.y >> 16))    + bf2f((us)(a3.y >> 16))    + bi.w;
    *(float4*)&x[base] = v;

    float s  = v.x + v.y + v.z + v.w;
    float sq = v.x * v.x + v.y * v.y + v.z * v.z + v.w * v.w;
    __shared__ float red[8];
    for (int o = 32; o > 0; o >>= 1) { s += __shfl_xor(s, o); sq += __shfl_xor(sq, o); }
    int wave = tid >> 6, lane = tid & 63;
    if (lane == 0) { red[wave] = s; red[4 + wave] = sq; }
    __syncthreads();
    if (tid == 0) {
        red[0] = red[0] + red[1] + red[2] + red[3];
        red[4] = red[4] + red[5] + red[6] + red[7];
    }
    __syncthreads();
    float mean = red[0] * (1.0f / E);
    float var  = red[4] * (1.0f / E) - mean * mean;
    float rstd = rsqrtf(var + 1e-5f);
    float4 wv = *(const float4*)&w[c];
    float4 bv = *(const float4*)&b[c];
    unsigned b0 = f2bf((v.x - mean) * rstd * wv.x + bv.x);
    unsigned b1 = f2bf((v.y - mean) * rstd * wv.y + bv.y);
    unsigned b2 = f2bf((v.z - mean) * rstd * wv.z + bv.z);
    unsigned b3 = f2bf((v.w - mean) * rstd * wv.w + bv.w);
    uint2 o; o.x = b0 | (b1 << 16); o.y = b2 | (b3 << 16);
    *(uint2*)&out[base] = o;
}

// ================================================================ 256x256 8-phase GEMM (T2+T3+T4+T5)
// ISVM: 0 = none, 1 = vmcnt(6), 2 = vmcnt(0) (peeled-tail drain)
#define GPH(dd, fb, STAGE, ISVM, IS12)                                              \
  {                                                                                 \
    bf16x8 afr0[2], afr1[2];                                                        \
    if ((fb) == 0) {                                                                \
      _Pragma("unroll")                                                             \
      for (int n = 0; n < 4; n++)                                                   \
        _Pragma("unroll")                                                           \
        for (int ks = 0; ks < 2; ks++)                                              \
          bfr[n][ks] = *(const bf16x8*)&lds[32768 + (dd) * 16384 +                  \
              (brow + n * 16) * 64 + ((ks * 4 + g4) ^ xg) * 8];                     \
    }                                                                               \
    _Pragma("unroll")                                                               \
    for (int ks = 0; ks < 2; ks++) {                                                \
      afr0[ks] = *(const bf16x8*)&lds[(dd) * 16384 + ((fb) >> 1) * 4096 +           \
          arow0 * 64 + ((ks * 4 + g4) ^ xg) * 8];                                   \
      afr1[ks] = *(const bf16x8*)&lds[(dd) * 16384 + ((fb) >> 1) * 4096 +           \
          arow1 * 64 + ((ks * 4 + g4) ^ xg) * 8];                                   \
    }                                                                               \
    STAGE;                                                                          \
    __builtin_amdgcn_sched_barrier(0);                                              \
    if (IS12) asm volatile("s_waitcnt lgkmcnt(8)" ::: "memory");                    \
    __builtin_amdgcn_s_barrier();                                                   \
    asm volatile("s_waitcnt lgkmcnt(0)" ::: "memory");                              \
    __builtin_amdgcn_sched_barrier(0);                                              \
    __builtin_amdgcn_s_setprio(1);                                                  \
    _Pragma("unroll")                                                               \
    for (int n = 0; n < 4; n++)                                                     \
      _Pragma("unroll")                                                             \
      for (int ks = 0; ks < 2; ks++) {                                              \
        acc[(fb)][n]     = __builtin_amdgcn_mfma_f32_16x16x32_bf16(afr0[ks], bfr[n][ks], acc[(fb)][n], 0, 0, 0);     \
        acc[(fb) + 1][n] = __builtin_amdgcn_mfma_f32_16x16x32_bf16(afr1[ks], bfr[n][ks], acc[(fb) + 1][n], 0, 0, 0); \
      }                                                                             \
    __builtin_amdgcn_s_setprio(0);                                                  \
    __builtin_amdgcn_sched_barrier(0);                                              \
    if ((ISVM) == 1) asm volatile("s_waitcnt vmcnt(6)" ::: "memory");               \
    if ((ISVM) == 2) asm volatile("s_waitcnt vmcnt(0)" ::: "memory");               \
    __builtin_amdgcn_s_barrier();                                                   \
  }

// SPLITK=0: sw -> (bm,bn) M-fastest over gemm_nwg blocks. SPLITK=1: kz chunks of K.
// WRITE_VT: qkv mode — V-tiles (bn>=2048) write transposed to vt[b][h][d][s].
// RIDER: blocks with wgid >= gemm_nwg grid-stride cast csrc(f32) -> cdst(bf16).
// Epilogue: LDS-transpose — scatter C into LDS, read back linear, 16B/lane stores.
template <int OUT_BF16, int ACT_GELU, int HAS_BIAS, int SPLITK, int WRITE_VT, int RIDER>
__global__ __launch_bounds__(512, 2) void gemm256(const us* __restrict__ A, int lda,
                                                  const us* __restrict__ Bw, int ldb,
                                                  const float* __restrict__ bias,
                                                  void* __restrict__ outp,
                                                  void* __restrict__ outp3,
                                                  us* __restrict__ vt,
                                                  const float* __restrict__ csrc,
                                                  us* __restrict__ cdst,
                                                  int dst_ld, int gemm_nwg,
                                                  int M, int N, int K, int ldo) {
    int tid = threadIdx.x;
    int wgid = blockIdx.x;
    if (RIDER && wgid >= gemm_nwg) {
        int nrb = gridDim.x - gemm_nwg;
        int rtid = (wgid - gemm_nwg) * 512 + tid;
        int nthr = nrb * 512;
        for (int j = rtid; j < 4 * E * E / 8; j += nthr) {
            f32x4 a = __builtin_nontemporal_load((const f32x4*)csrc + 2 * (size_t)j);
            f32x4 b = __builtin_nontemporal_load((const f32x4*)csrc + 2 * (size_t)j + 1);
            uint4 o;
            o.x = f2bf(a[0]) | ((unsigned)f2bf(a[1]) << 16);
            o.y = f2bf(a[2]) | ((unsigned)f2bf(a[3]) << 16);
            o.z = f2bf(b[0]) | ((unsigned)f2bf(b[1]) << 16);
            o.w = f2bf(b[2]) | ((unsigned)f2bf(b[3]) << 16);
            int n = j >> 7, c8 = (j & 127) << 3;
            *(uint4*)&cdst[(size_t)n * dst_ld + c8] = o;
        }
        return;
    }
    __shared__ us lds[65536];
    int chunk = gemm_nwg >> 3;
    int sw = (wgid & 7) * chunk + (wgid >> 3);
    int MB = M >> 8;
    int bm, bn;
    us* outb;
    float* outf = (float*)outp;
    if (SPLITK) {
        int ntile = MB * (N >> 8);
        int kz = sw / ntile;
        int rem = sw % ntile;
        bm = (rem % MB) * 256;
        bn = (rem / MB) * 256;
        A  += (size_t)kz * K;
        Bw += (size_t)kz * K;
        outb = (kz < 3) ? (us*)outp + (size_t)kz * M * ldo : (us*)outp3;
    } else {
        bm = (sw % MB) * 256;
        bn = (sw / MB) * 256;
        outb = (us*)outp;
    }
    int w = tid >> 6, lane = tid & 63;
    int wr = w >> 2, wc = w & 3;
    int l15 = lane & 15, g4 = lane >> 4;
    int xg = l15 & 7;
    int arow0 = (wr ? 32 : 0) + l15;
    int arow1 = arow0 + 16;
    int brow = wc * 64 + l15;
    int NT = K >> 6;

    f32x4 acc[8][4] = {};
    bf16x8 bfr[4][2];

    auto stA = [&](int u, int dd, int h) {
        #pragma unroll
        for (int i = 0; i < 2; i++) {
            int k = tid + i * 512;
            int q = 2 * h + (k >> 9);
            int r = (k >> 3) & 63;
            int tr = q * 32 + (r & 31) + ((r >> 5) << 7);
            int gp = (k & 7) ^ (r & 7);
            gld16(A + (size_t)(bm + tr) * lda + u * 64 + gp * 8,
                  &lds[dd * 16384 + h * 8192 + k * 8]);
        }
    };
    auto stB = [&](int u, int dd, int h) {
        #pragma unroll
        for (int i = 0; i < 2; i++) {
            int k = tid + i * 512;
            int row = h * 128 + (k >> 3);
            int gp = (k & 7) ^ ((k >> 3) & 7);
            gld16(Bw + (size_t)(bn + row) * ldb + u * 64 + gp * 8,
                  &lds[32768 + dd * 16384 + h * 8192 + k * 8]);
        }
    };

    stB(0, 0, 0); stB(0, 0, 1); stA(0, 0, 0); stA(0, 0, 1);
    stB(1, 1, 0); stB(1, 1, 1); stA(1, 1, 0);
    __builtin_amdgcn_sched_barrier(0);
    asm volatile("s_waitcnt vmcnt(6)" ::: "memory");
    __builtin_amdgcn_s_barrier();

    #pragma unroll 1
    for (int t = 0; t < NT - 2; t += 2) {
        GPH(0, 0, stA(t + 1, 1, 1), 0, 1)
        GPH(0, 2, stB(t + 2, 0, 0), 0, 0)
        GPH(0, 4, stB(t + 2, 0, 1), 0, 0)
        GPH(0, 6, stA(t + 2, 0, 0), 1, 0)
        GPH(1, 0, stA(t + 2, 0, 1), 0, 1)
        GPH(1, 2, stB(t + 3, 1, 0), 0, 0)
        GPH(1, 4, stB(t + 3, 1, 1), 0, 0)
        GPH(1, 6, stA(t + 3, 1, 0), 1, 0)
    }
    // peeled final iteration (tiles NT-2, NT-1): no beyond-range prefetch.
    GPH(0, 0, stA(NT - 1, 1, 1), 0, 1)
    GPH(0, 2, , 0, 0)
    GPH(0, 4, , 0, 0)
    GPH(0, 6, , 2, 0)
    GPH(1, 0, , 0, 1)
    GPH(1, 2, , 0, 0)
    GPH(1, 4, , 0, 0)
    GPH(1, 6, , 0, 0)
    // (last GPH ends with s_barrier: all LDS reads complete -> lds reusable)

    if (WRITE_VT && bn >= 2048) {
        // V tile: write transposed, packed 4 consecutive s per lane (8B store)
        #pragma unroll
        for (int mf = 0; mf < 8; mf++)
            #pragma unroll
            for (int n = 0; n < 4; n++) {
                int r = bm + wr * 128 + mf * 16 + g4 * 4;
                int c = bn + wc * 64 + n * 16 + l15;
                int hh = (c - 2048) >> 6, d = (c - 2048) & 63;
                int bq = r >> 11, s = r & (S - 1);
                float bv = HAS_BIAS ? bias[c] : 0.0f;
                unsigned o0 = f2bf(acc[mf][n][0] + bv) | ((unsigned)f2bf(acc[mf][n][1] + bv) << 16);
                unsigned o1 = f2bf(acc[mf][n][2] + bv) | ((unsigned)f2bf(acc[mf][n][3] + bv) << 16);
                uint2 pk; pk.x = o0; pk.y = o1;
                *(uint2*)&vt[(((size_t)(bq * H + hh) * 64 + d) << 11) + s] = pk;
            }
        return;
    }

    if (OUT_BF16) {
        // scatter C (bf16) into LDS [256][256], then linear read-back, 16B/lane stores
        #pragma unroll
        for (int mf = 0; mf < 8; mf++)
            #pragma unroll
            for (int n = 0; n < 4; n++)
                #pragma unroll
                for (int j = 0; j < 4; j++) {
                    int r = wr * 128 + mf * 16 + g4 * 4 + j;
                    int c = wc * 64 + n * 16 + l15;
                    float v = acc[mf][n][j];
                    if (HAS_BIAS) v += bias[bn + c];
                    if (ACT_GELU) v = gelu(v);
                    lds[r * 256 + c] = f2bf(v);
                }
        __builtin_amdgcn_s_barrier();
        #pragma unroll
        for (int it = 0; it < 16; it++) {
            int idx = it * 512 + tid;
            int row = idx >> 5, c16 = idx & 31;
            u32x4 v = *(const u32x4*)&lds[row * 256 + c16 * 8];
            *(u32x4*)&outb[(size_t)(bm + row) * ldo + bn + c16 * 8] = v;
        }
    } else {
        // f32: two 128-col halves through LDS [256][128] f32
        float* lf = (float*)lds;
        #pragma unroll
        for (int half = 0; half < 2; half++) {
            if ((wc >> 1) == half) {
                #pragma unroll
                for (int mf = 0; mf < 8; mf++)
                    #pragma unroll
                    for (int n = 0; n < 4; n++)
                        #pragma unroll
                        for (int j = 0; j < 4; j++) {
                            int r = wr * 128 + mf * 16 + g4 * 4 + j;
                            int c = (wc & 1) * 64 + n * 16 + l15;
                            float v = acc[mf][n][j];
                            if (HAS_BIAS) v += bias[bn + half * 128 + c];
                            lf[r * 128 + c] = v;
                        }
            }
            __builtin_amdgcn_s_barrier();
            #pragma unroll
            for (int it = 0; it < 16; it++) {
                int idx = it * 512 + tid;
                int row = idx >> 5, c16 = idx & 31;
                f32x4 v = *(const f32x4*)&lf[row * 128 + c16 * 4];
                __builtin_nontemporal_store(v,
                    (f32x4*)&outf[(size_t)(bm + row) * ldo + bn + half * 128 + c16 * 4]);
            }
            if (half == 0) __builtin_amdgcn_s_barrier();
        }
    }
}

// ---------------------------------------------------------------- flash attention: 8 waves, QBLK=128, KVB=64
// causal load-balance: b==1 blocks take reversed qt; softmax in log2 domain (exp2, no mul)
__global__ __launch_bounds__(512, 4) void attn_kernel(const us* __restrict__ qkv,
                                                      const us* __restrict__ vT,
                                                      float* __restrict__ x) {
    int qt = blockIdx.x, h = blockIdx.y, b = blockIdx.z;
    if (b == 1) qt = (S / 128 - 1) - qt;   // heavy+light pairing per CU
    int tid = threadIdx.x;
    int w = tid >> 6, lane = tid & 63;
    int l15 = lane & 15, g4 = lane >> 4;
    int s0 = qt * 128;
    int qrow_base = s0 + w * 16;
    const size_t qbase = (size_t)b * S * 3072;
    const size_t vtbase = ((size_t)(b * H + h) * 64) * S;

    __shared__ us K_lds[2][64 * 64];
    __shared__ us VT_lds[2][64 * 64];
    __shared__ us P_lds[8][16 * 72];

    bf16x8 q[2];
    #pragma unroll
    for (int dc = 0; dc < 2; dc++) {
        q[dc] = *(const bf16x8*)&qkv[qbase + (size_t)(qrow_base + l15) * 3072 + h * 64 + dc * 32 + 8 * g4];
        us* qq = (us*)&q[dc];
        #pragma unroll
        for (int e = 0; e < 8; e++) qq[e] = f2bf(bf2f(qq[e]) * 0.18033688f);  // 0.125 * log2(e)
    }

    f32x4 O[4] = {};
    float m_run[4], l_part[4];
    #pragma unroll
    for (int j = 0; j < 4; j++) { m_run[j] = -INFINITY; l_part[j] = 0.0f; }

    int lastt = 2 * qt + 1;
    {
        int p = tid, row = p >> 3, cc = p & 7;
        int scc = cc ^ (row & 7);
        gld16(&qkv[qbase + (size_t)(0 + row) * 3072 + 1024 + h * 64 + scc * 8], &K_lds[0][p * 8]);
        gld16(&vT[vtbase + (size_t)row * S + 0 + scc * 8], &VT_lds[0][p * 8]);
    }
    __syncthreads();

    for (int t = 0; t <= lastt; t++) {
        int bb = t & 1;
        if (t < lastt) {
            int p = tid, row = p >> 3, cc = p & 7;
            int scc = cc ^ (row & 7);
            gld16(&qkv[qbase + (size_t)((t + 1) * 64 + row) * 3072 + 1024 + h * 64 + scc * 8], &K_lds[bb ^ 1][p * 8]);
            gld16(&vT[vtbase + (size_t)row * S + (t + 1) * 64 + scc * 8], &VT_lds[bb ^ 1][p * 8]);
        }
        int k0 = t * 64;
        if (k0 <= qrow_base + 15) {
            f32x4 sf[4];
            __builtin_amdgcn_s_setprio(1);
            #pragma unroll
            for (int c = 0; c < 4; c++) {
                f32x4 z = {};
                int row = c * 16 + l15;
                #pragma unroll
                for (int dc = 0; dc < 2; dc++) {
                    int ch = (dc * 4 + g4) ^ (row & 7);
                    bf16x8 kb = *(const bf16x8*)&K_lds[bb][row * 64 + ch * 8];
                    z = __builtin_amdgcn_mfma_f32_16x16x32_bf16(q[dc], kb, z, 0, 0, 0);
                }
                sf[c] = z;
            }
            __builtin_amdgcn_s_setprio(0);
            bool needmask = (k0 + 63 > qrow_base);
            float vv[4][4], tmr[4];
            #pragma unroll
            for (int j = 0; j < 4; j++) {
                int qrow = qrow_base + g4 * 4 + j;
                float v0 = sf[0][j], v1 = sf[1][j];
                float v2 = sf[2][j], v3 = sf[3][j];
                if (needmask) {
                    if (k0 +      l15 > qrow) v0 = -INFINITY;
                    if (k0 + 16 + l15 > qrow) v1 = -INFINITY;
                    if (k0 + 32 + l15 > qrow) v2 = -INFINITY;
                    if (k0 + 48 + l15 > qrow) v3 = -INFINITY;
                }
                float tm = fmaxf(fmaxf(v0, v1), fmaxf(v2, v3));
                tm = fmaxf(tm, __shfl_xor(tm, 1, 16));
                tm = fmaxf(tm, __shfl_xor(tm, 2, 16));
                tm = fmaxf(tm, __shfl_xor(tm, 4, 16));
                tm = fmaxf(tm, __shfl_xor(tm, 8, 16));
                tmr[j] = tm;
                vv[0][j] = v0; vv[1][j] = v1; vv[2][j] = v2; vv[3][j] = v3;
            }
            // defer-max threshold 8 in nat-log => 8*log2e ~ 11.54 in log2 domain
            bool grow = (tmr[0] > m_run[0] + 11.54f) || (tmr[1] > m_run[1] + 11.54f) ||
                        (tmr[2] > m_run[2] + 11.54f) || (tmr[3] > m_run[3] + 11.54f);
            bool skip = !__any(grow);
            float pr[4][4], alpha[4];
            #pragma unroll
            for (int j = 0; j < 4; j++) {
                float mnew = skip ? m_run[j] : fmaxf(m_run[j], tmr[j]);
                float p0 = exp2f(vv[0][j] - mnew), p1 = exp2f(vv[1][j] - mnew);
                float p2 = exp2f(vv[2][j] - mnew), p3 = exp2f(vv[3][j] - mnew);
                float sum4 = (p0 + p1) + (p2 + p3);
                if (skip) {
                    l_part[j] += sum4;
                } else {
                    alpha[j] = exp2f(m_run[j] - mnew);
                    l_part[j] = l_part[j] * alpha[j] + sum4;
                    m_run[j] = mnew;
                }
                pr[0][j] = p0; pr[1][j] = p1; pr[2][j] = p2; pr[3][j] = p3;
            }
            if (!skip) {
                #pragma unroll
                for (int f = 0; f < 4; f++)
                    #pragma unroll
                    for (int j = 0; j < 4; j++) O[f][j] *= alpha[j];
            }
            us* Pw = &P_lds[w][0];
            #pragma unroll
            for (int c = 0; c < 4; c++)
                #pragma unroll
                for (int j = 0; j < 4; j++)
                    Pw[(g4 * 4 + j) * 72 + c * 16 + l15] = f2bf(pr[c][j]);
            __builtin_amdgcn_s_setprio(1);
            #pragma unroll
            for (int kc = 0; kc < 2; kc++) {
                bf16x8 pa = *(const bf16x8*)&Pw[l15 * 72 + kc * 32 + g4 * 8];
                #pragma unroll
                for (int dt = 0; dt < 4; dt++) {
                    int row = dt * 16 + l15;
                    int ch = (kc * 4 + g4) ^ (row & 7);
                    bf16x8 vb = *(const bf16x8*)&VT_lds[bb][row * 64 + ch * 8];
                    O[dt] = __builtin_amdgcn_mfma_f32_16x16x32_bf16(pa, vb, O[dt], 0, 0, 0);
                }
            }
            __builtin_amdgcn_s_setprio(0);
        }
        __syncthreads();
    }
    float l_run[4];
    #pragma unroll
    for (int j = 0; j < 4; j++) {
        float l = l_part[j];
        l += __shfl_xor(l, 1, 16);
        l += __shfl_xor(l, 2, 16);
        l += __shfl_xor(l, 4, 16);
        l += __shfl_xor(l, 8, 16);
        l_run[j] = l;
    }
    #pragma unroll
    for (int dt = 0; dt < 4; dt++)
        #pragma unroll
        for (int j = 0; j < 4; j++) {
            size_t o = ((size_t)b * S + qrow_base + g4 * 4 + j) * E + h * 64 + dt * 16 + l15;
            x[o] += O[dt][j] / l_run[j];
        }
}

// ---------------------------------------------------------------- launch
extern "C" void kernel_launch(void* const* d_in, const int* in_sizes, int n_in,
                              void* d_out, int out_size, void* d_ws, size_t ws_size,
                              hipStream_t stream) {
    const int*   idx    = (const int*)d_in[0];
    const float* tok    = (const float*)d_in[1];
    const float* pos    = (const float*)d_in[2];
    const float* qkv_w  = (const float*)d_in[3];
    const float* qkv_b  = (const float*)d_in[4];
    const float* ln1_w  = (const float*)d_in[5];
    const float* ln1_b  = (const float*)d_in[6];
    const float* ln2_w  = (const float*)d_in[7];
    const float* ln2_b  = (const float*)d_in[8];
    const float* ff1_w  = (const float*)d_in[9];
    const float* ff1_b  = (const float*)d_in[10];
    const float* ff2_w  = (const float*)d_in[11];
    const float* ff2_b  = (const float*)d_in[12];
    const float* fin_w  = (const float*)d_in[13];
    const float* fin_b  = (const float*)d_in[14];
    const float* proj_w = (const float*)d_in[15];

    char* ws = (char*)d_ws;
    float* x    = (float*)ws;                          // 16.78 MB f32 residual
    us*    xn   = (us*)(ws + 16777216);                // 8.39 MB bf16 LN out
    us*    qkvb = (us*)(ws + 25165824);                // 25.17 MB bf16 qkv (Q,K) / ff1-w rider (V-third) / ff2 partials 0-2
    us*    hbuf = (us*)(ws + 50331648);                // 33.55 MB bf16 ff hidden
    us*    wbuf = (us*)(ws + 83886080);                // 8.39 MB bf16 qkv / ff2 weights
    us*    vTb  = (us*)(ws + 92274688);                // 8.39 MB bf16 V^T / ff2 partial 3
    us*    pbuf = qkvb;                                // 65.5 MB proj weights (qkvb..wbuf span, free then)

    embed_ln<<<NTOK, 256, 0, stream>>>(idx, tok, pos, ln1_w, ln1_b, x, xn);
    for (int l = 0; l < DEPTH; l++) {
        cast_kernel<<<1536, 256, 0, stream>>>(qkv_w + (size_t)l * 3 * E * E, wbuf, 3 * E * E / 8);
        // qkv (192 GEMM blocks) + 64 rider blocks casting ff1_w into qkvb's dead V-third (ld 3072)
        gemm256<1, 0, 1, 0, 1, 1><<<256, 512, 0, stream>>>(
            xn, E, wbuf, E, qkv_b + l * 3 * E, qkvb, nullptr, vTb,
            ff1_w + (size_t)l * 4 * E * E, qkvb + 2048, 3072, 192, NTOK, 3 * E, E, 3 * E);
        attn_kernel<<<dim3(S / 128, H, BB), 512, 0, stream>>>(qkvb, vTb, x);
        ln_kernel<<<NTOK, 256, 0, stream>>>(x, ln2_w + l * E, ln2_b + l * E, xn);
        // ff1 (256 GEMM blocks, B = ff1 weights in V-third, ldb 3072) + 64 riders casting ff2_w -> wbuf (flat)
        gemm256<1, 1, 1, 0, 0, 1><<<320, 512, 0, stream>>>(
            xn, E, qkvb + 2048, 3072, ff1_b + l * 4 * E, hbuf, nullptr, nullptr,
            ff2_w + (size_t)l * E * 4 * E, wbuf, 1024, 256, NTOK, 4 * E, E, 4 * E);
        // ff2: 256^2 8-phase split-K x4 (grid 256 = 1 block/CU), bf16 partials
        gemm256<1, 0, 0, 1, 0, 0><<<256, 512, 0, stream>>>(
            hbuf, 4 * E, wbuf, 4 * E, nullptr, qkvb, vTb, nullptr,
            nullptr, nullptr, 0, 256, NTOK, E, E, E);
        const float* nw = (l < DEPTH - 1) ? (ln1_w + (l + 1) * E) : fin_w;
        const float* nb = (l < DEPTH - 1) ? (ln1_b + (l + 1) * E) : fin_b;
        combine_ln<<<NTOK, 256, 0, stream>>>(qkvb, vTb, ff2_b + l * E, x, nw, nb, xn);
    }
    cast_kernel<<<16000, 256, 0, stream>>>(proj_w, pbuf, V * E / 8);
    gemm256<0, 0, 0, 0, 0, 0><<<2000, 512, 0, stream>>>(
        xn, E, pbuf, E, nullptr, d_out, nullptr, nullptr,
        nullptr, nullptr, 0, 2000, NTOK, V, E, V);
}